// Round 15
// baseline (264.313 us; speedup 1.0000x reference)
//
#include <hip/hip_runtime.h>

// CausalSALayer: post-norm transformer decoder layer on gfx950.
// B=2, N=2048, D=1024, H=16, dk=64, FFN=4096. bf16 MFMA compute, f32 accum.

#define DEV __device__ __forceinline__

typedef __attribute__((ext_vector_type(4)))  float f32x4;
typedef __attribute__((ext_vector_type(16))) float f32x16;
typedef __attribute__((ext_vector_type(8)))  short s16x8;

static constexpr int Bb   = 2;
static constexpr int NN   = 2048;
static constexpr int DM   = 1024;
static constexpr int HH   = 16;
static constexpr int DK   = 64;
static constexpr int FF   = 4096;
static constexpr int ROWS = Bb * NN;  // 4096

#define AS1(p) ((const __attribute__((address_space(1))) void*)(p))
#define AS3(p) ((__attribute__((address_space(3))) void*)(p))

DEV unsigned short f2bf(float f) {
  unsigned u = __float_as_uint(f);
  u += 0x7fff + ((u >> 16) & 1);   // RNE
  return (unsigned short)(u >> 16);
}
DEV float bf2f(unsigned short u) {
  return __uint_as_float((unsigned)u << 16);
}
DEV float fexp2(float x) {
  float r;
  asm("v_exp_f32 %0, %1" : "=v"(r) : "v"(x));
  return r;
}
DEV unsigned cvtpk(float lo, float hi) {
  unsigned r;
  asm("v_cvt_pk_bf16_f32 %0, %1, %2" : "=v"(r) : "v"(lo), "v"(hi));
  return r;
}

// ---------------- fused cast f32 -> bf16: all 7 tensors in one launch --------
__global__ __launch_bounds__(256) void k_cast7(
    const float* __restrict__ tgt, const float* __restrict__ Wq,
    const float* __restrict__ Wk, const float* __restrict__ Wv,
    const float* __restrict__ Wo, const float* __restrict__ W1,
    const float* __restrict__ W2,
    ushort* __restrict__ xb, ushort* __restrict__ wqb,
    ushort* __restrict__ w1b, ushort* __restrict__ w2b) {
  const int i = blockIdx.x * 256 + threadIdx.x;
  constexpr int S0 = 1048576;   // tgt float4s
  constexpr int S1 = 262144;    // per-DxD-weight float4s
  const float4* src;
  ushort* dstp;
  if (i < S0)               { src = (const float4*)tgt + i;            dstp = xb  + (size_t)i * 4; }
  else if (i < S0 + S1)     { src = (const float4*)Wq + (i - S0);      dstp = wqb + (size_t)(i - S0) * 4; }
  else if (i < S0 + 2 * S1) { src = (const float4*)Wk + (i - S0 - S1); dstp = wqb + (size_t)(i - S0) * 4; }
  else if (i < S0 + 3 * S1) { src = (const float4*)Wv + (i - S0 - 2 * S1); dstp = wqb + (size_t)(i - S0) * 4; }
  else if (i < S0 + 4 * S1) { src = (const float4*)Wo + (i - S0 - 3 * S1); dstp = wqb + (size_t)(i - S0) * 4; }
  else if (i < 3 * S0)      { src = (const float4*)W1 + (i - 2 * S0);  dstp = w1b + (size_t)(i - 2 * S0) * 4; }
  else                      { src = (const float4*)W2 + (i - 3 * S0);  dstp = w2b + (size_t)(i - 3 * S0) * 4; }
  float4 v = *src;
  ushort4 o;
  o.x = f2bf(v.x); o.y = f2bf(v.y); o.z = f2bf(v.z); o.w = f2bf(v.w);
  *reinterpret_cast<ushort4*>(dstp) = o;
}

// ---------------- GEMM: double-buffer, counted-vmcnt pipeline (T3/T4) ------------
// EPI 0: C->bf16 ; 1: C+bias,gelu->bf16 ; 2: C+bias+resid(bf16)->f32 ; 3: raw f32.
// QKV: outputs to q|k contig; K-third pre-swizzled; V-third fused transpose->vT.
template <int EPI, int BN, bool QKV, int SPLITK>
__global__ __launch_bounds__(256) void k_gemm(
    const ushort* __restrict__ A, const ushort* __restrict__ Bt,
    const float* __restrict__ bias, const ushort* __restrict__ resid,
    ushort* __restrict__ Cb, float* __restrict__ Cf,
    int K, int nbx) {
  __shared__ ushort As[2][128][32];
  __shared__ ushort Bs[2][BN][32];

  const int t = threadIdx.x;
  const int lane = t & 63, w = t >> 6;
  const int lr = lane & 15, lg = lane >> 4;
  const int lrow = lane >> 2, lc8 = (lane & 3) * 8;

  const int nwg = gridDim.x;
  const int bid = blockIdx.x;
  const int q8 = nwg >> 3, r8 = nwg & 7;
  const int xcd = bid & 7, lin = bid >> 3;
  int wg = (xcd < r8 ? xcd * (q8 + 1) : r8 * (q8 + 1) + (xcd - r8) * q8) + lin;
  int kc = 0;
  if constexpr (SPLITK == 2) { kc = wg & 1; wg >>= 1; }
  const int band = wg / (4 * nbx);
  const int inn  = wg % (4 * nbx);
  const int by = band * 4 + (inn & 3);
  const int bx = inn >> 2;

  const int bRow = by * 128;
  const int bCol = bx * BN;
  const int Kc = K / SPLITK;
  const int kofs = kc * Kc;
  const int nk = Kc / 32;

  constexpr int NW = BN / 32;
  const int wRow = (w >> 1) * 64, wCol = (w & 1) * (BN / 2);

  f32x4 acc[4][NW];
#pragma unroll
  for (int m = 0; m < 4; ++m)
#pragma unroll
    for (int n = 0; n < NW; ++n) acc[m][n] = (f32x4){0.f, 0.f, 0.f, 0.f};

  auto stage = [&](int buf, int tile) {
    const int kb = kofs + tile * 32;
#pragma unroll
    for (int i = 0; i < 2; ++i) {
      int rr = w * 32 + i * 16;
      __builtin_amdgcn_global_load_lds(
          AS1(A + (size_t)(bRow + rr + lrow) * K + kb + lc8),
          AS3(&As[buf][rr][0]), 16, 0, 0);
    }
#pragma unroll
    for (int i = 0; i < BN / 64; ++i) {
      int rr = w * (BN / 4) + i * 16;
      __builtin_amdgcn_global_load_lds(
          AS1(Bt + (size_t)(bCol + rr + lrow) * K + kb + lc8),
          AS3(&Bs[buf][rr][0]), 16, 0, 0);
    }
  };

  stage(0, 0);
  for (int tt = 0; tt < nk; ++tt) {
    const int cur = tt & 1;
    if (tt + 1 < nk) {
      stage(cur ^ 1, tt + 1);
      if constexpr (BN == 128) asm volatile("s_waitcnt vmcnt(4)" ::: "memory");
      else                     asm volatile("s_waitcnt vmcnt(3)" ::: "memory");
    } else {
      asm volatile("s_waitcnt vmcnt(0)" ::: "memory");
    }
    __builtin_amdgcn_s_barrier();
    __builtin_amdgcn_sched_barrier(0);

    s16x8 af[4], bfr[NW];
#pragma unroll
    for (int m = 0; m < 4; ++m)
      af[m] = *reinterpret_cast<const s16x8*>(&As[cur][wRow + m * 16 + lr][lg * 8]);
#pragma unroll
    for (int n = 0; n < NW; ++n)
      bfr[n] = *reinterpret_cast<const s16x8*>(&Bs[cur][wCol + n * 16 + lr][lg * 8]);
#pragma unroll
    for (int m = 0; m < 4; ++m)
#pragma unroll
      for (int n = 0; n < NW; ++n)
        acc[m][n] = __builtin_amdgcn_mfma_f32_16x16x32_bf16(af[m], bfr[n], acc[m][n], 0, 0, 0);

    asm volatile("s_waitcnt lgkmcnt(0)" ::: "memory");
    __builtin_amdgcn_s_barrier();
    __builtin_amdgcn_sched_barrier(0);
  }

  // ---- epilogue ----
  ushort* CbOut = Cb;
  int colBase = bCol, Ncols = nbx * BN, third = 0;
  if (QKV) {
    third = bCol >> 10;
    CbOut = Cb + (size_t)third * ROWS * DM;
    colBase = bCol & 1023;
    Ncols = DM;
  }
#pragma unroll
  for (int m = 0; m < 4; ++m) {
    int gr = bRow + wRow + m * 16 + lg * 4;
#pragma unroll
    for (int n = 0; n < NW; ++n) {
      int gc = colBase + wCol + n * 16 + lr;
      if (QKV && third == 2) {
        int h = gc >> 6, d = gc & 63;
        int b = gr >> 11, ntok = gr & (NN - 1);
        size_t basev = ((size_t)(b * HH + h) * DK + d) * NN;
        int nb = ntok & ~63, c = (ntok >> 3) & 7, j0 = ntok & 7;
        ushort4 ov;
        ov.x = f2bf(acc[m][n][0]);
        ov.y = f2bf(acc[m][n][1]);
        ov.z = f2bf(acc[m][n][2]);
        ov.w = f2bf(acc[m][n][3]);
        ushort* VT = Cb + (size_t)3 * ROWS * DM;
        *reinterpret_cast<ushort4*>(VT + basev + nb + ((c ^ (d & 7)) << 3) + j0) = ov;
        continue;
      }
      float bv = (EPI == 1 || EPI == 2) ? bias[gc] : 0.0f;
#pragma unroll
      for (int r = 0; r < 4; ++r) {
        int nr = gr + r;
        float v = acc[m][n][r] + bv;
        if (EPI == 3) {
          Cf[((size_t)kc * ROWS + nr) * Ncols + gc] = v;
        } else if (EPI == 2) {
          size_t idx = (size_t)nr * Ncols + gc;
          Cf[idx] = v + bf2f(resid[idx]);
        } else if (EPI == 1) {
          size_t idx = (size_t)nr * Ncols + gc;
          float u = v + 0.044715f * v * v * v;
          float g = v / (1.0f + __expf(-1.5957691216057308f * u));
          CbOut[idx] = f2bf(g);
        } else {
          int gcs = gc;
          if (QKV && third == 1)
            gcs = (gc & ~63) | ((gc ^ ((nr & 7) << 3)) & 63);
          CbOut[(size_t)nr * Ncols + gcs] = f2bf(v);
        }
      }
    }
  }
}

// ======== k_gemm9: deep-pipeline 256^2 GEMM for FFN1 (bias+gelu) ========
// 512 thr = 8 waves (2x4). BK=32. 4 LDS buffers (128KB), 3 tiles prefetched;
// counted vmcnt(4*inflight) -> loads NEVER drain mid-loop (T4). Fragment-major
// 1KB chunks: ds_read = chunkbase + lane*16 (stride-1, 0 bank conflicts).
__global__ __launch_bounds__(512) void k_gemm9(
    const ushort* __restrict__ A, const ushort* __restrict__ Bt,
    const float* __restrict__ bias, ushort* __restrict__ Cb,
    int K, int nbx) {
  __shared__ ushort As[4][8192];   // 16 chunks x 1KB per buffer
  __shared__ ushort Bs[4][8192];

  const int t = threadIdx.x;
  const int lane = t & 63, w = t >> 6;
  const int lr = lane & 15, lg = lane >> 4;
  const int wr = w >> 2, wc = w & 3;

  const int nwg = gridDim.x;
  const int bid = blockIdx.x;
  const int q8 = nwg >> 3, r8 = nwg & 7;
  const int xcd = bid & 7, lin = bid >> 3;
  const int wg = (xcd < r8 ? xcd * (q8 + 1) : r8 * (q8 + 1) + (xcd - r8) * q8) + lin;
  const int band = wg / (4 * nbx);
  const int inn  = wg % (4 * nbx);
  const int by = band * 4 + (inn & 3);
  const int bx = inn >> 2;

  const int bRow = by * 256;
  const int bCol = bx * 256;
  const int nk = K / 32;

  f32x4 acc[8][4];
#pragma unroll
  for (int m = 0; m < 8; ++m)
#pragma unroll
    for (int n = 0; n < 4; ++n) acc[m][n] = (f32x4){0.f, 0.f, 0.f, 0.f};

  char* AsB = (char*)As;
  char* BsB = (char*)Bs;

  // stage one tile (per wave: 2 A chunks + 2 B chunks = 4 gload_lds)
  auto stage = [&](int buf, int tile) {
    const int kb = tile * 32;
#pragma unroll
    for (int i = 0; i < 2; ++i) {
      const int c = w * 2 + i;    // chunk 0..15: rows c*16..c*16+15
      __builtin_amdgcn_global_load_lds(
          AS1(A + (size_t)(bRow + c * 16 + lr) * K + kb + lg * 8),
          AS3(AsB + buf * 16384 + c * 1024), 16, 0, 0);
      __builtin_amdgcn_global_load_lds(
          AS1(Bt + (size_t)(bCol + c * 16 + lr) * K + kb + lg * 8),
          AS3(BsB + buf * 16384 + c * 1024), 16, 0, 0);
    }
  };

  stage(0, 0);
  stage(1, 1);
  stage(2, 2);
  for (int tt = 0; tt < nk; ++tt) {
    const int cur = tt & 3;
    const int rem = nk - 1 - tt;          // tiles after current
    if (rem >= 3) {
      stage((tt + 3) & 3, tt + 3);
      asm volatile("s_waitcnt vmcnt(12)" ::: "memory");
    } else if (rem == 2) {
      asm volatile("s_waitcnt vmcnt(8)" ::: "memory");
    } else if (rem == 1) {
      asm volatile("s_waitcnt vmcnt(4)" ::: "memory");
    } else {
      asm volatile("s_waitcnt vmcnt(0)" ::: "memory");
    }
    __builtin_amdgcn_s_barrier();
    __builtin_amdgcn_sched_barrier(0);

    const char* Ab = AsB + cur * 16384 + (wr * 8) * 1024 + lane * 16;
    const char* Bb = BsB + cur * 16384 + (wc * 4) * 1024 + lane * 16;
    s16x8 af[8], bfr[4];
#pragma unroll
    for (int m = 0; m < 8; ++m)
      af[m] = *reinterpret_cast<const s16x8*>(Ab + m * 1024);
#pragma unroll
    for (int n = 0; n < 4; ++n)
      bfr[n] = *reinterpret_cast<const s16x8*>(Bb + n * 1024);

    __builtin_amdgcn_s_setprio(1);
#pragma unroll
    for (int m = 0; m < 8; ++m)
#pragma unroll
      for (int n = 0; n < 4; ++n)
        acc[m][n] = __builtin_amdgcn_mfma_f32_16x16x32_bf16(af[m], bfr[n], acc[m][n], 0, 0, 0);
    __builtin_amdgcn_s_setprio(0);

    asm volatile("s_waitcnt lgkmcnt(0)" ::: "memory");
    __builtin_amdgcn_s_barrier();
    __builtin_amdgcn_sched_barrier(0);
  }

  // ---- epilogue: bias + gelu -> bf16 ----
  const int Ncols = nbx * 256;
#pragma unroll
  for (int m = 0; m < 8; ++m) {
    int gr = bRow + wr * 128 + m * 16 + lg * 4;
#pragma unroll
    for (int n = 0; n < 4; ++n) {
      int gc = bCol + wc * 64 + n * 16 + lr;
      float bv = bias[gc];
#pragma unroll
      for (int r = 0; r < 4; ++r) {
        int nr = gr + r;
        float v = acc[m][n][r] + bv;
        float u = v + 0.044715f * v * v * v;
        float g = v / (1.0f + __expf(-1.5957691216057308f * u));
        Cb[(size_t)nr * Ncols + gc] = f2bf(g);
      }
    }
  }
}

// ---------------- LayerNorm over D=1024 rows ----------------
template <int MODE>
__global__ __launch_bounds__(256) void k_ln(const void* __restrict__ inp,
                                            const float* __restrict__ p0,
                                            const float* __restrict__ p1,
                                            const float* __restrict__ pb,
                                            const float* __restrict__ g,
                                            const float* __restrict__ bta,
                                            float* __restrict__ outf,
                                            ushort* __restrict__ outb) {
  const int row = blockIdx.x;
  const int t = threadIdx.x;
  float4 v;
  if (MODE == 0) {
    v = reinterpret_cast<const float4*>((const float*)inp + (size_t)row * DM)[t];
  } else {
    ushort4 xv = reinterpret_cast<const ushort4*>((const ushort*)inp + (size_t)row * DM)[t];
    float4 a = reinterpret_cast<const float4*>(p0 + (size_t)row * DM)[t];
    float4 b = reinterpret_cast<const float4*>(p1 + (size_t)row * DM)[t];
    float4 c = reinterpret_cast<const float4*>(pb)[t];
    v.x = bf2f(xv.x) + a.x + b.x + c.x;
    v.y = bf2f(xv.y) + a.y + b.y + c.y;
    v.z = bf2f(xv.z) + a.z + b.z + c.z;
    v.w = bf2f(xv.w) + a.w + b.w + c.w;
  }
  float s1 = v.x + v.y + v.z + v.w;
  float s2 = v.x * v.x + v.y * v.y + v.z * v.z + v.w * v.w;
#pragma unroll
  for (int m = 32; m; m >>= 1) {
    s1 += __shfl_xor(s1, m, 64);
    s2 += __shfl_xor(s2, m, 64);
  }
  __shared__ float red[2][4];
  if ((t & 63) == 0) { red[0][t >> 6] = s1; red[1][t >> 6] = s2; }
  __syncthreads();
  s1 = red[0][0] + red[0][1] + red[0][2] + red[0][3];
  s2 = red[1][0] + red[1][1] + red[1][2] + red[1][3];
  const float mu = s1 * (1.0f / DM);
  const float var = s2 * (1.0f / DM) - mu * mu;
  const float rstd = rsqrtf(var + 1e-5f);
  float4 gv = reinterpret_cast<const float4*>(g)[t];
  float4 bv = reinterpret_cast<const float4*>(bta)[t];
  float4 o;
  o.x = (v.x - mu) * rstd * gv.x + bv.x;
  o.y = (v.y - mu) * rstd * gv.y + bv.y;
  o.z = (v.z - mu) * rstd * gv.z + bv.z;
  o.w = (v.w - mu) * rstd * gv.w + bv.w;
  if (MODE == 1) {
    reinterpret_cast<float4*>(outf + (size_t)row * DM)[t] = o;
  } else {
    ushort4 ob;
    ob.x = f2bf(o.x); ob.y = f2bf(o.y); ob.z = f2bf(o.z); ob.w = f2bf(o.w);
    reinterpret_cast<ushort4*>(outb + (size_t)row * DM)[t] = ob;
  }
}

// ---------------- causal flash attention: XCD-pinned, <=8-tile segments ----
static __device__ const unsigned char SCHED40[40][2] = {
  {15,0},{15,1},{15,2},{15,3}, {14,0},{14,1},{14,2},{14,3},
  {13,0},{13,1},{13,2},{13,3}, {12,0},{12,1},{12,2},{12,3},
  {11,0},{11,1},{11,2}, {10,0},{10,1},{10,2},
  {9,0},{9,1},{9,2}, {8,0},{8,1},{8,2},
  {7,0},{7,1}, {6,0},{6,1}, {5,0},{5,1}, {4,0},{4,1},
  {3,0},{2,0},{1,0},{0,0}};

__global__ __launch_bounds__(256) void k_attn(const ushort* __restrict__ Q,
                                              const ushort* __restrict__ Kb,
                                              const ushort* __restrict__ vT,
                                              ushort* __restrict__ O,
                                              float* __restrict__ Op,
                                              float* __restrict__ ml) {
  __shared__ ushort Ks[2][64 * 64];
  __shared__ ushort Vs[2][64 * 64];

  const int t = threadIdx.x;
  const int bid = blockIdx.x;
  const int xcd = bid & 7, j = bid >> 3;    // j in [0,160)
  const int head = j & 3, e = j >> 2;       // e in [0,40)
  const int qi = SCHED40[e][0], seg = SCHED40[e][1];
  const int bh = xcd * 4 + head;
  const int ntiles = 2 * qi + 2;
  const int nseg = (2 * qi + 9) >> 3;       // 1,2,3,4
  const int tb = ntiles / nseg, rem = ntiles % nseg;
  const int kt0 = seg * tb + (seg < rem ? seg : rem);
  const int kt1 = kt0 + tb + (seg < rem ? 1 : 0);

  const int lane = t & 63, wid = t >> 6;
  const int l31 = lane & 31, hi = lane >> 5;
  const int q0w = qi * 128 + wid * 32;
  const size_t qbase = ((size_t)(bh >> 4) * NN) * DM + (bh & 15) * DK;
  const size_t vbase = (size_t)bh * DK * NN;

  const float C = 0.18033688011112043f;   // 0.125 * log2(e)

  s16x8 qf[4];
#pragma unroll
  for (int c = 0; c < 4; ++c)
    qf[c] = *reinterpret_cast<const s16x8*>(Q + qbase + (size_t)(q0w + l31) * DM + c * 16 + hi * 8);

  float mrun = -1e30f, lrun = 0.f, negcm = 1e30f;
  f32x16 accO[2];
#pragma unroll
  for (int dt = 0; dt < 2; ++dt)
#pragma unroll
    for (int r = 0; r < 16; ++r) accO[dt][r] = 0.f;

  auto stage = [&](int buf, int kt) {
    const int kk = kt * 64;
#pragma unroll
    for (int i = 0; i < 2; ++i) {
      int row0 = wid * 16 + i * 8;
      __builtin_amdgcn_global_load_lds(
          AS1(Kb + qbase + (size_t)(kk + row0 + (lane >> 3)) * DM + (lane & 7) * 8),
          AS3(&Ks[buf][row0 * 64]), 16, 0, 0);
      __builtin_amdgcn_global_load_lds(
          AS1(vT + vbase + (size_t)(row0 + (lane >> 3)) * NN + kk + (lane & 7) * 8),
          AS3(&Vs[buf][row0 * 64]), 16, 0, 0);
    }
  };

  stage(0, kt0);
  for (int kt = kt0, li = 0; kt < kt1; ++kt, ++li) {
    const int cur = li & 1;
    const int kk = kt * 64;
    __syncthreads();
    if (kt + 1 < kt1) stage(cur ^ 1, kt + 1);

    if (kk <= q0w + 31) {
      const char* KsB = (const char*)Ks[cur];
      const char* VsB = (const char*)Vs[cur];
      const bool diag = (kk + 64 > q0w);
      const int nsub = (kk + 32 <= q0w + 31) ? 2 : 1;   // wave-uniform

      f32x16 st[2];
      __builtin_amdgcn_s_setprio(1);
#pragma unroll
      for (int sub = 0; sub < 2; ++sub) {
        if (sub >= nsub) break;
#pragma unroll
        for (int r = 0; r < 16; ++r) st[sub][r] = 0.f;
        const int row = sub * 32 + l31;
        const int swz = (row & 7) << 4;
#pragma unroll
        for (int c = 0; c < 4; ++c) {
          s16x8 kf = *reinterpret_cast<const s16x8*>(KsB + row * 128 + ((c * 32 + hi * 16) ^ swz));
          st[sub] = __builtin_amdgcn_mfma_f32_32x32x16_bf16(kf, qf[c], st[sub], 0, 0, 0);
        }
      }
      __builtin_amdgcn_s_setprio(0);

      const int q = q0w + l31;
      float p[32];
#pragma unroll
      for (int sub = 0; sub < 2; ++sub) {
        if (sub >= nsub) break;
#pragma unroll
        for (int r = 0; r < 16; ++r) {
          float v = st[sub][r];
          if (diag) {
            int kl = sub * 32 + (r & 3) + 8 * (r >> 2) + 4 * hi;
            if (kk + kl > q) v = -1e30f;
          }
          p[sub * 16 + r] = v;
        }
      }
      float m8[8];
#pragma unroll
      for (int i = 0; i < 8; ++i) {
        float x = fmaxf(p[i], p[i + 8]);
        if (nsub == 2) x = fmaxf(fmaxf(p[i + 16], p[i + 24]), x);
        m8[i] = x;
      }
      float rm = fmaxf(fmaxf(fmaxf(m8[0], m8[1]), fmaxf(m8[2], m8[3])),
                       fmaxf(fmaxf(m8[4], m8[5]), fmaxf(m8[6], m8[7])));
      rm = fmaxf(rm, __shfl_xor(rm, 32, 64));

      if (__any(rm > mrun)) {
        const float mn = fmaxf(mrun, rm);
        const float alpha = fexp2(C * (mrun - mn));
        mrun = mn;
        negcm = -C * mn;
        lrun *= alpha;
#pragma unroll
        for (int dt = 0; dt < 2; ++dt) accO[dt] *= alpha;
      }

#pragma unroll
      for (int sub = 0; sub < 2; ++sub) {
        if (sub >= nsub) break;
#pragma unroll
        for (int i = 0; i < 16; ++i)
          p[sub * 16 + i] = fexp2(fmaf(p[sub * 16 + i], C, negcm));
      }
      float a[16];
#pragma unroll
      for (int i = 0; i < 16; ++i) a[i] = (nsub == 2) ? (p[i] + p[i + 16]) : p[i];
#pragma unroll
      for (int s = 8; s; s >>= 1)
#pragma unroll
        for (int i = 0; i < 8; ++i) if (i < s) a[i] += a[i + s];
      lrun += a[0] + __shfl_xor(a[0], 32, 64);

      s16x8 pf[4];
#pragma unroll
      for (int sub = 0; sub < 2; ++sub) {
        if (sub >= nsub) break;
#pragma unroll
        for (int hf = 0; hf < 2; ++hf) {
          const float* pp = &p[sub * 16 + hf * 8];
          unsigned X0 = cvtpk(pp[0], pp[1]);
          unsigned X1 = cvtpk(pp[2], pp[3]);
          unsigned Y0 = cvtpk(pp[4], pp[5]);
          unsigned Y1 = cvtpk(pp[6], pp[7]);
          asm volatile("v_permlane32_swap_b32 %0, %1" : "+v"(X0), "+v"(Y0));
          asm volatile("v_permlane32_swap_b32 %0, %1" : "+v"(X1), "+v"(Y1));
          union { unsigned u[4]; s16x8 v; } uu;
          uu.u[0] = X0; uu.u[1] = X1; uu.u[2] = Y0; uu.u[3] = Y1;
          pf[sub * 2 + hf] = uu.v;
        }
      }

      __builtin_amdgcn_s_setprio(1);
#pragma unroll
      for (int dt = 0; dt < 2; ++dt) {
        const int d = dt * 32 + l31;
        const int vswz = (d & 7) << 4;
#pragma unroll
        for (int kc = 0; kc < 4; ++kc) {
          if (kc >= nsub * 2) break;
          s16x8 vf = *reinterpret_cast<const s16x8*>(VsB + d * 128 + ((kc * 32 + hi * 16) ^ vswz));
          accO[dt] = __builtin_amdgcn_mfma_f32_32x32x16_bf16(vf, pf[kc], accO[dt], 0, 0, 0);
        }
      }
      __builtin_amdgcn_s_setprio(0);
    }
  }

  // ---- epilogue ----
  if (nseg == 1) {
    const int q = q0w + l31;
    const float inv = 1.0f / lrun;
#pragma unroll
    for (int dt = 0; dt < 2; ++dt)
#pragma unroll
      for (int rg = 0; rg < 4; ++rg) {
        int d0 = 8 * rg + 4 * hi + 32 * dt;
        ushort4 ov;
        ov.x = f2bf(accO[dt][rg * 4 + 0] * inv);
        ov.y = f2bf(accO[dt][rg * 4 + 1] * inv);
        ov.z = f2bf(accO[dt][rg * 4 + 2] * inv);
        ov.w = f2bf(accO[dt][rg * 4 + 3] * inv);
        *reinterpret_cast<ushort4*>(O + qbase + (size_t)q * DM + d0) = ov;
      }
  } else {
    const int pidx = (bh * 12 + (qi - 4)) * 4 + seg;
    float* op = Op + (size_t)pidx * (128 * 64);
    const int row = wid * 32 + l31;
#pragma unroll
    for (int dt = 0; dt < 2; ++dt)
#pragma unroll
      for (int rg = 0; rg < 4; ++rg) {
        int d0 = 8 * rg + 4 * hi + 32 * dt;
        f32x4 v4 = { accO[dt][rg * 4 + 0], accO[dt][rg * 4 + 1],
                     accO[dt][rg * 4 + 2], accO[dt][rg * 4 + 3] };
        *reinterpret_cast<f32x4*>(op + (size_t)row * 64 + d0) = v4;
      }
    if (hi == 0) {
      ml[(size_t)pidx * 256 + row * 2 + 0] = mrun;
      ml[(size_t)pidx * 256 + row * 2 + 1] = lrun;
    }
  }
}

// ---------------- merge split-KV partials (up to 4-way) ----------------
__global__ __launch_bounds__(256) void k_amerge(const float* __restrict__ Op,
                                                const float* __restrict__ ml,
                                                ushort* __restrict__ O) {
  const int bid = blockIdx.x;
  const int bh = bid / 12, qq = bid % 12;
  const int qi = qq + 4;
  const int nseg = (2 * qi + 9) >> 3;       // 2,3,4
  const int t = threadIdx.x;
  const int row = t >> 1, dh = (t & 1) * 32;
  const float C = 0.18033688011112043f;
  const int pbase = (bh * 12 + qq) * 4;

  float M = -1e30f;
  for (int s = 0; s < nseg; ++s)
    M = fmaxf(M, ml[(size_t)(pbase + s) * 256 + row * 2 + 0]);
  float wsum = 0.f;
  for (int s = 0; s < nseg; ++s) {
    float ms = ml[(size_t)(pbase + s) * 256 + row * 2 + 0];
    float ls = ml[(size_t)(pbase + s) * 256 + row * 2 + 1];
    wsum += ls * fexp2(C * (ms - M));
  }
  const float inv = 1.0f / wsum;

  f32x4 acc[8];
#pragma unroll
  for (int i = 0; i < 8; ++i) acc[i] = (f32x4){0.f, 0.f, 0.f, 0.f};
  for (int s = 0; s < nseg; ++s) {
    float wsc = fexp2(C * (ml[(size_t)(pbase + s) * 256 + row * 2 + 0] - M));
    const float* os = Op + (size_t)(pbase + s) * (128 * 64) + (size_t)row * 64 + dh;
#pragma unroll
    for (int i = 0; i < 8; ++i) {
      f32x4 v = reinterpret_cast<const f32x4*>(os)[i];
      acc[i] += v * wsc;
    }
  }

  const int b = bh >> 4, h = bh & 15;
  const int n = qi * 128 + row;
  ushort* dst = O + ((size_t)(b * NN + n)) * DM + h * DK + dh;
#pragma unroll
  for (int i = 0; i < 8; ++i) {
    ushort4 ov;
    ov.x = f2bf(acc[i][0] * inv);
    ov.y = f2bf(acc[i][1] * inv);
    ov.z = f2bf(acc[i][2] * inv);
    ov.w = f2bf(acc[i][3] * inv);
    reinterpret_cast<ushort4*>(dst)[i] = ov;
  }
}

// ---------------- launch ----------------
extern "C" void kernel_launch(void* const* d_in, const int* in_sizes, int n_in,
                              void* d_out, int out_size, void* d_ws, size_t ws_size,
                              hipStream_t stream) {
  const float* tgt = (const float*)d_in[0];
  const float* Wq  = (const float*)d_in[3];
  const float* Wk  = (const float*)d_in[4];
  const float* Wv  = (const float*)d_in[5];
  const float* Wo  = (const float*)d_in[6];
  const float* bo  = (const float*)d_in[7];
  const float* W1  = (const float*)d_in[8];
  const float* b1  = (const float*)d_in[9];
  const float* W2  = (const float*)d_in[10];
  const float* b2  = (const float*)d_in[11];
  const float* g1  = (const float*)d_in[12];
  const float* be1 = (const float*)d_in[13];
  const float* g2  = (const float*)d_in[14];
  const float* be2 = (const float*)d_in[15];

  char* ws = (char*)d_ws;
  size_t off = 0;
  auto alloc = [&](size_t bytes) {
    void* p = ws + off;
    off += (bytes + 255) & ~(size_t)255;
    return p;
  };
  ushort* xb   = (ushort*)alloc((size_t)ROWS * DM * 2);
  ushort* wqb  = (ushort*)alloc((size_t)DM * DM * 2);   // wq|wk|wv contiguous
  ushort* wkb  = (ushort*)alloc((size_t)DM * DM * 2);
  ushort* wvb  = (ushort*)alloc((size_t)DM * DM * 2);
  ushort* wob  = (ushort*)alloc((size_t)DM * DM * 2);
  ushort* w1b  = (ushort*)alloc((size_t)FF * DM * 2);
  ushort* w2b  = (ushort*)alloc((size_t)DM * FF * 2);
  ushort* qbuf = (ushort*)alloc((size_t)ROWS * DM * 2); // q|k|v|vT contiguous
  ushort* kbuf = (ushort*)alloc((size_t)ROWS * DM * 2);
  ushort* vbuf = (ushort*)alloc((size_t)ROWS * DM * 2); // unused (V fused to vT)
  ushort* vtb  = (ushort*)alloc((size_t)ROWS * DM * 2);
  ushort* atnb = (ushort*)alloc((size_t)ROWS * DM * 2);
  float*  h1   = (float*)alloc((size_t)ROWS * DM * 4);
  float*  x1f  = (float*)alloc((size_t)ROWS * DM * 4);  // kept for layout (unused)
  ushort* x1b  = (ushort*)alloc((size_t)ROWS * DM * 2);
  ushort* t1b  = (ushort*)alloc((size_t)ROWS * FF * 2);
  float*  mlb  = (float*)alloc((size_t)1536 * 256 * 4);      // m,l partials
  float*  Opb  = h1;            // attn O-partials overlay dead h1/x1f region
  float*  pp   = (float*)qbuf;  // FFN2 split-K partials overlay dead q/k/v/vT
  (void)ws_size; (void)in_sizes; (void)n_in; (void)out_size;
  (void)wkb; (void)wvb; (void)kbuf; (void)vbuf; (void)vtb; (void)x1f;

  dim3 blk(256);
  k_cast7<<<dim3(16384), blk, 0, stream>>>(tgt, Wq, Wk, Wv, Wo, W1, W2,
                                           xb, wqb, w1b, w2b);

  // fused QKV (K-third pre-swizzled; V-third fused transpose -> vtb)
  k_gemm<0, 128, true, 1><<<dim3(24 * 32), blk, 0, stream>>>(
      xb, wqb, nullptr, nullptr, qbuf, nullptr, DM, 24);

  k_attn<<<dim3(1280), blk, 0, stream>>>(qbuf, kbuf, vtb, atnb, Opb, mlb);
  k_amerge<<<dim3(384), blk, 0, stream>>>(Opb, mlb, atnb);

  // O-projection + bo + residual(xb, bf16) -> f32 h1 (overwrites dead partials)
  k_gemm<2, 64, false, 1><<<dim3(16 * 32), blk, 0, stream>>>(
      atnb, wob, bo, xb, nullptr, h1, DM, 16);
  // LN1: h1 -> x1b (bf16 only)
  k_ln<0><<<dim3(ROWS), blk, 0, stream>>>(h1, nullptr, nullptr, nullptr,
                                          g1, be1, nullptr, x1b);

  // FFN1: deep-pipeline 256^2 (4-buffer, counted vmcnt, 0-conflict LDS)
  k_gemm9<<<dim3(256), dim3(512), 0, stream>>>(x1b, w1b, b1, t1b, DM, 16);

  // FFN2: split-K=2, raw f32 partials into pp (q/k/v/vT region, now dead)
  k_gemm<3, 64, false, 2><<<dim3(2 * 16 * 32), blk, 0, stream>>>(
      t1b, w2b, nullptr, nullptr, nullptr, pp, FF, 16);
  // LN2: x1b(bf16) + split-K reduce + b2 -> d_out (f32)
  k_ln<1><<<dim3(ROWS), blk, 0, stream>>>(x1b, pp, pp + (size_t)ROWS * DM, b2,
                                          g2, be2, (float*)d_out, nullptr);
}

// Round 16
// 258.222 us; speedup vs baseline: 1.0236x; 1.0236x over previous
//
#include <hip/hip_runtime.h>

// CausalSALayer: post-norm transformer decoder layer on gfx950.
// B=2, N=2048, D=1024, H=16, dk=64, FFN=4096. bf16 MFMA compute, f32 accum.
// Best-known configuration (R14): dbuf counted-vmcnt GEMMs, fused QKV w/
// K-swizzle + V-transpose epilogues, XCD-pinned segment-split flash attention,
// split-K FFN2 reduced inside LN2, bf16 residuals.

#define DEV __device__ __forceinline__

typedef __attribute__((ext_vector_type(4)))  float f32x4;
typedef __attribute__((ext_vector_type(16))) float f32x16;
typedef __attribute__((ext_vector_type(8)))  short s16x8;

static constexpr int Bb   = 2;
static constexpr int NN   = 2048;
static constexpr int DM   = 1024;
static constexpr int HH   = 16;
static constexpr int DK   = 64;
static constexpr int FF   = 4096;
static constexpr int ROWS = Bb * NN;  // 4096

#define AS1(p) ((const __attribute__((address_space(1))) void*)(p))
#define AS3(p) ((__attribute__((address_space(3))) void*)(p))

DEV unsigned short f2bf(float f) {
  unsigned u = __float_as_uint(f);
  u += 0x7fff + ((u >> 16) & 1);   // RNE
  return (unsigned short)(u >> 16);
}
DEV float bf2f(unsigned short u) {
  return __uint_as_float((unsigned)u << 16);
}
DEV float fexp2(float x) {
  float r;
  asm("v_exp_f32 %0, %1" : "=v"(r) : "v"(x));
  return r;
}
DEV unsigned cvtpk(float lo, float hi) {
  unsigned r;
  asm("v_cvt_pk_bf16_f32 %0, %1, %2" : "=v"(r) : "v"(lo), "v"(hi));
  return r;
}

// ---------------- fused cast f32 -> bf16: all 7 tensors in one launch --------
__global__ __launch_bounds__(256) void k_cast7(
    const float* __restrict__ tgt, const float* __restrict__ Wq,
    const float* __restrict__ Wk, const float* __restrict__ Wv,
    const float* __restrict__ Wo, const float* __restrict__ W1,
    const float* __restrict__ W2,
    ushort* __restrict__ xb, ushort* __restrict__ wqb,
    ushort* __restrict__ w1b, ushort* __restrict__ w2b) {
  const int i = blockIdx.x * 256 + threadIdx.x;
  constexpr int S0 = 1048576;   // tgt float4s
  constexpr int S1 = 262144;    // per-DxD-weight float4s
  const float4* src;
  ushort* dstp;
  if (i < S0)               { src = (const float4*)tgt + i;            dstp = xb  + (size_t)i * 4; }
  else if (i < S0 + S1)     { src = (const float4*)Wq + (i - S0);      dstp = wqb + (size_t)(i - S0) * 4; }
  else if (i < S0 + 2 * S1) { src = (const float4*)Wk + (i - S0 - S1); dstp = wqb + (size_t)(i - S0) * 4; }
  else if (i < S0 + 3 * S1) { src = (const float4*)Wv + (i - S0 - 2 * S1); dstp = wqb + (size_t)(i - S0) * 4; }
  else if (i < S0 + 4 * S1) { src = (const float4*)Wo + (i - S0 - 3 * S1); dstp = wqb + (size_t)(i - S0) * 4; }
  else if (i < 3 * S0)      { src = (const float4*)W1 + (i - 2 * S0);  dstp = w1b + (size_t)(i - 2 * S0) * 4; }
  else                      { src = (const float4*)W2 + (i - 3 * S0);  dstp = w2b + (size_t)(i - 3 * S0) * 4; }
  float4 v = *src;
  ushort4 o;
  o.x = f2bf(v.x); o.y = f2bf(v.y); o.z = f2bf(v.z); o.w = f2bf(v.w);
  *reinterpret_cast<ushort4*>(dstp) = o;
}

// ---------------- GEMM: double-buffer, counted-vmcnt pipeline (T3/T4) ------------
// EPI 0: C->bf16 ; 1: C+bias,gelu->bf16 ; 2: C+bias+resid(bf16)->f32 ; 3: raw f32.
// QKV: outputs to q|k contig; K-third pre-swizzled; V-third fused transpose->vT.
template <int EPI, int BN, bool QKV, int SPLITK>
__global__ __launch_bounds__(256) void k_gemm(
    const ushort* __restrict__ A, const ushort* __restrict__ Bt,
    const float* __restrict__ bias, const ushort* __restrict__ resid,
    ushort* __restrict__ Cb, float* __restrict__ Cf,
    int K, int nbx) {
  __shared__ ushort As[2][128][32];
  __shared__ ushort Bs[2][BN][32];

  const int t = threadIdx.x;
  const int lane = t & 63, w = t >> 6;
  const int lr = lane & 15, lg = lane >> 4;
  const int lrow = lane >> 2, lc8 = (lane & 3) * 8;

  const int nwg = gridDim.x;
  const int bid = blockIdx.x;
  const int q8 = nwg >> 3, r8 = nwg & 7;
  const int xcd = bid & 7, lin = bid >> 3;
  int wg = (xcd < r8 ? xcd * (q8 + 1) : r8 * (q8 + 1) + (xcd - r8) * q8) + lin;
  int kc = 0;
  if constexpr (SPLITK == 2) { kc = wg & 1; wg >>= 1; }
  const int band = wg / (4 * nbx);
  const int inn  = wg % (4 * nbx);
  const int by = band * 4 + (inn & 3);
  const int bx = inn >> 2;

  const int bRow = by * 128;
  const int bCol = bx * BN;
  const int Kc = K / SPLITK;
  const int kofs = kc * Kc;
  const int nk = Kc / 32;

  constexpr int NW = BN / 32;
  const int wRow = (w >> 1) * 64, wCol = (w & 1) * (BN / 2);

  f32x4 acc[4][NW];
#pragma unroll
  for (int m = 0; m < 4; ++m)
#pragma unroll
    for (int n = 0; n < NW; ++n) acc[m][n] = (f32x4){0.f, 0.f, 0.f, 0.f};

  auto stage = [&](int buf, int tile) {
    const int kb = kofs + tile * 32;
#pragma unroll
    for (int i = 0; i < 2; ++i) {
      int rr = w * 32 + i * 16;
      __builtin_amdgcn_global_load_lds(
          AS1(A + (size_t)(bRow + rr + lrow) * K + kb + lc8),
          AS3(&As[buf][rr][0]), 16, 0, 0);
    }
#pragma unroll
    for (int i = 0; i < BN / 64; ++i) {
      int rr = w * (BN / 4) + i * 16;
      __builtin_amdgcn_global_load_lds(
          AS1(Bt + (size_t)(bCol + rr + lrow) * K + kb + lc8),
          AS3(&Bs[buf][rr][0]), 16, 0, 0);
    }
  };

  stage(0, 0);
  for (int tt = 0; tt < nk; ++tt) {
    const int cur = tt & 1;
    if (tt + 1 < nk) {
      stage(cur ^ 1, tt + 1);   // buffer read at tt-1; safe after its trailing barrier
      if constexpr (BN == 128) asm volatile("s_waitcnt vmcnt(4)" ::: "memory");
      else                     asm volatile("s_waitcnt vmcnt(3)" ::: "memory");
    } else {
      asm volatile("s_waitcnt vmcnt(0)" ::: "memory");
    }
    __builtin_amdgcn_s_barrier();
    __builtin_amdgcn_sched_barrier(0);

    s16x8 af[4], bfr[NW];
#pragma unroll
    for (int m = 0; m < 4; ++m)
      af[m] = *reinterpret_cast<const s16x8*>(&As[cur][wRow + m * 16 + lr][lg * 8]);
#pragma unroll
    for (int n = 0; n < NW; ++n)
      bfr[n] = *reinterpret_cast<const s16x8*>(&Bs[cur][wCol + n * 16 + lr][lg * 8]);
#pragma unroll
    for (int m = 0; m < 4; ++m)
#pragma unroll
      for (int n = 0; n < NW; ++n)
        acc[m][n] = __builtin_amdgcn_mfma_f32_16x16x32_bf16(af[m], bfr[n], acc[m][n], 0, 0, 0);

    asm volatile("s_waitcnt lgkmcnt(0)" ::: "memory");
    __builtin_amdgcn_s_barrier();
    __builtin_amdgcn_sched_barrier(0);
  }

  // ---- epilogue ----
  ushort* CbOut = Cb;
  int colBase = bCol, Ncols = nbx * BN, third = 0;
  if (QKV) {
    third = bCol >> 10;
    CbOut = Cb + (size_t)third * ROWS * DM;
    colBase = bCol & 1023;
    Ncols = DM;
  }
#pragma unroll
  for (int m = 0; m < 4; ++m) {
    int gr = bRow + wRow + m * 16 + lg * 4;
#pragma unroll
    for (int n = 0; n < NW; ++n) {
      int gc = colBase + wCol + n * 16 + lr;
      if (QKV && third == 2) {
        // V-third: fused transpose to vT[bh][d][n], 8-chunk swizzled
        int h = gc >> 6, d = gc & 63;
        int b = gr >> 11, ntok = gr & (NN - 1);
        size_t basev = ((size_t)(b * HH + h) * DK + d) * NN;
        int nb = ntok & ~63, c = (ntok >> 3) & 7, j0 = ntok & 7;
        ushort4 ov;
        ov.x = f2bf(acc[m][n][0]);
        ov.y = f2bf(acc[m][n][1]);
        ov.z = f2bf(acc[m][n][2]);
        ov.w = f2bf(acc[m][n][3]);
        ushort* VT = Cb + (size_t)3 * ROWS * DM;   // vtb region
        *reinterpret_cast<ushort4*>(VT + basev + nb + ((c ^ (d & 7)) << 3) + j0) = ov;
        continue;
      }
      float bv = (EPI == 1 || EPI == 2) ? bias[gc] : 0.0f;
#pragma unroll
      for (int r = 0; r < 4; ++r) {
        int nr = gr + r;
        float v = acc[m][n][r] + bv;
        if (EPI == 3) {
          Cf[((size_t)kc * ROWS + nr) * Ncols + gc] = v;
        } else if (EPI == 2) {
          size_t idx = (size_t)nr * Ncols + gc;
          Cf[idx] = v + bf2f(resid[idx]);
        } else if (EPI == 1) {
          size_t idx = (size_t)nr * Ncols + gc;
          float u = v + 0.044715f * v * v * v;
          float g = v / (1.0f + __expf(-1.5957691216057308f * u));
          CbOut[idx] = f2bf(g);
        } else {
          int gcs = gc;
          if (QKV && third == 1)   // pre-swizzle K rows for attn's linear gload_lds
            gcs = (gc & ~63) | ((gc ^ ((nr & 7) << 3)) & 63);
          CbOut[(size_t)nr * Ncols + gcs] = f2bf(v);
        }
      }
    }
  }
}

// ---------------- LayerNorm over D=1024 rows ----------------
// MODE 0: in f32 -> outb bf16 only (LN1).
// MODE 1: in bf16 + p0 + p1 + pb reduce -> outf f32 (LN2, split-K fused).
template <int MODE>
__global__ __launch_bounds__(256) void k_ln(const void* __restrict__ inp,
                                            const float* __restrict__ p0,
                                            const float* __restrict__ p1,
                                            const float* __restrict__ pb,
                                            const float* __restrict__ g,
                                            const float* __restrict__ bta,
                                            float* __restrict__ outf,
                                            ushort* __restrict__ outb) {
  const int row = blockIdx.x;
  const int t = threadIdx.x;
  float4 v;
  if (MODE == 0) {
    v = reinterpret_cast<const float4*>((const float*)inp + (size_t)row * DM)[t];
  } else {
    ushort4 xv = reinterpret_cast<const ushort4*>((const ushort*)inp + (size_t)row * DM)[t];
    float4 a = reinterpret_cast<const float4*>(p0 + (size_t)row * DM)[t];
    float4 b = reinterpret_cast<const float4*>(p1 + (size_t)row * DM)[t];
    float4 c = reinterpret_cast<const float4*>(pb)[t];
    v.x = bf2f(xv.x) + a.x + b.x + c.x;
    v.y = bf2f(xv.y) + a.y + b.y + c.y;
    v.z = bf2f(xv.z) + a.z + b.z + c.z;
    v.w = bf2f(xv.w) + a.w + b.w + c.w;
  }
  float s1 = v.x + v.y + v.z + v.w;
  float s2 = v.x * v.x + v.y * v.y + v.z * v.z + v.w * v.w;
#pragma unroll
  for (int m = 32; m; m >>= 1) {
    s1 += __shfl_xor(s1, m, 64);
    s2 += __shfl_xor(s2, m, 64);
  }
  __shared__ float red[2][4];
  if ((t & 63) == 0) { red[0][t >> 6] = s1; red[1][t >> 6] = s2; }
  __syncthreads();
  s1 = red[0][0] + red[0][1] + red[0][2] + red[0][3];
  s2 = red[1][0] + red[1][1] + red[1][2] + red[1][3];
  const float mu = s1 * (1.0f / DM);
  const float var = s2 * (1.0f / DM) - mu * mu;
  const float rstd = rsqrtf(var + 1e-5f);
  float4 gv = reinterpret_cast<const float4*>(g)[t];
  float4 bv = reinterpret_cast<const float4*>(bta)[t];
  float4 o;
  o.x = (v.x - mu) * rstd * gv.x + bv.x;
  o.y = (v.y - mu) * rstd * gv.y + bv.y;
  o.z = (v.z - mu) * rstd * gv.z + bv.z;
  o.w = (v.w - mu) * rstd * gv.w + bv.w;
  if (MODE == 1) {
    reinterpret_cast<float4*>(outf + (size_t)row * DM)[t] = o;
  } else {
    ushort4 ob;
    ob.x = f2bf(o.x); ob.y = f2bf(o.y); ob.z = f2bf(o.z); ob.w = f2bf(o.w);
    reinterpret_cast<ushort4*>(outb + (size_t)row * DM)[t] = ob;
  }
}

// ---------------- causal flash attention: XCD-pinned, <=8-tile segments ----
static __device__ const unsigned char SCHED40[40][2] = {
  {15,0},{15,1},{15,2},{15,3}, {14,0},{14,1},{14,2},{14,3},
  {13,0},{13,1},{13,2},{13,3}, {12,0},{12,1},{12,2},{12,3},
  {11,0},{11,1},{11,2}, {10,0},{10,1},{10,2},
  {9,0},{9,1},{9,2}, {8,0},{8,1},{8,2},
  {7,0},{7,1}, {6,0},{6,1}, {5,0},{5,1}, {4,0},{4,1},
  {3,0},{2,0},{1,0},{0,0}};

__global__ __launch_bounds__(256) void k_attn(const ushort* __restrict__ Q,
                                              const ushort* __restrict__ Kb,
                                              const ushort* __restrict__ vT,
                                              ushort* __restrict__ O,
                                              float* __restrict__ Op,
                                              float* __restrict__ ml) {
  __shared__ ushort Ks[2][64 * 64];
  __shared__ ushort Vs[2][64 * 64];

  const int t = threadIdx.x;
  const int bid = blockIdx.x;
  const int xcd = bid & 7, j = bid >> 3;    // j in [0,160)
  const int head = j & 3, e = j >> 2;       // e in [0,40)
  const int qi = SCHED40[e][0], seg = SCHED40[e][1];
  const int bh = xcd * 4 + head;
  const int ntiles = 2 * qi + 2;
  const int nseg = (2 * qi + 9) >> 3;       // 1,2,3,4
  const int tb = ntiles / nseg, rem = ntiles % nseg;
  const int kt0 = seg * tb + (seg < rem ? seg : rem);
  const int kt1 = kt0 + tb + (seg < rem ? 1 : 0);

  const int lane = t & 63, wid = t >> 6;
  const int l31 = lane & 31, hi = lane >> 5;
  const int q0w = qi * 128 + wid * 32;
  const size_t qbase = ((size_t)(bh >> 4) * NN) * DM + (bh & 15) * DK;
  const size_t vbase = (size_t)bh * DK * NN;

  const float C = 0.18033688011112043f;   // 0.125 * log2(e)

  s16x8 qf[4];
#pragma unroll
  for (int c = 0; c < 4; ++c)
    qf[c] = *reinterpret_cast<const s16x8*>(Q + qbase + (size_t)(q0w + l31) * DM + c * 16 + hi * 8);

  float mrun = -1e30f, lrun = 0.f, negcm = 1e30f;
  f32x16 accO[2];
#pragma unroll
  for (int dt = 0; dt < 2; ++dt)
#pragma unroll
    for (int r = 0; r < 16; ++r) accO[dt][r] = 0.f;

  auto stage = [&](int buf, int kt) {
    const int kk = kt * 64;
#pragma unroll
    for (int i = 0; i < 2; ++i) {
      int row0 = wid * 16 + i * 8;
      __builtin_amdgcn_global_load_lds(
          AS1(Kb + qbase + (size_t)(kk + row0 + (lane >> 3)) * DM + (lane & 7) * 8),
          AS3(&Ks[buf][row0 * 64]), 16, 0, 0);
      __builtin_amdgcn_global_load_lds(
          AS1(vT + vbase + (size_t)(row0 + (lane >> 3)) * NN + kk + (lane & 7) * 8),
          AS3(&Vs[buf][row0 * 64]), 16, 0, 0);
    }
  };

  stage(0, kt0);
  for (int kt = kt0, li = 0; kt < kt1; ++kt, ++li) {
    const int cur = li & 1;
    const int kk = kt * 64;
    __syncthreads();
    if (kt + 1 < kt1) stage(cur ^ 1, kt + 1);

    if (kk <= q0w + 31) {
      const char* KsB = (const char*)Ks[cur];
      const char* VsB = (const char*)Vs[cur];
      const bool diag = (kk + 64 > q0w);
      const int nsub = (kk + 32 <= q0w + 31) ? 2 : 1;   // wave-uniform

      f32x16 st[2];
      __builtin_amdgcn_s_setprio(1);
#pragma unroll
      for (int sub = 0; sub < 2; ++sub) {
        if (sub >= nsub) break;
#pragma unroll
        for (int r = 0; r < 16; ++r) st[sub][r] = 0.f;
        const int row = sub * 32 + l31;
        const int swz = (row & 7) << 4;
#pragma unroll
        for (int c = 0; c < 4; ++c) {
          s16x8 kf = *reinterpret_cast<const s16x8*>(KsB + row * 128 + ((c * 32 + hi * 16) ^ swz));
          st[sub] = __builtin_amdgcn_mfma_f32_32x32x16_bf16(kf, qf[c], st[sub], 0, 0, 0);
        }
      }
      __builtin_amdgcn_s_setprio(0);

      const int q = q0w + l31;
      float p[32];
#pragma unroll
      for (int sub = 0; sub < 2; ++sub) {
        if (sub >= nsub) break;
#pragma unroll
        for (int r = 0; r < 16; ++r) {
          float v = st[sub][r];
          if (diag) {
            int kl = sub * 32 + (r & 3) + 8 * (r >> 2) + 4 * hi;
            if (kk + kl > q) v = -1e30f;
          }
          p[sub * 16 + r] = v;
        }
      }
      float m8[8];
#pragma unroll
      for (int i = 0; i < 8; ++i) {
        float x = fmaxf(p[i], p[i + 8]);
        if (nsub == 2) x = fmaxf(fmaxf(p[i + 16], p[i + 24]), x);
        m8[i] = x;
      }
      float rm = fmaxf(fmaxf(fmaxf(m8[0], m8[1]), fmaxf(m8[2], m8[3])),
                       fmaxf(fmaxf(m8[4], m8[5]), fmaxf(m8[6], m8[7])));
      rm = fmaxf(rm, __shfl_xor(rm, 32, 64));

      if (__any(rm > mrun)) {
        const float mn = fmaxf(mrun, rm);
        const float alpha = fexp2(C * (mrun - mn));
        mrun = mn;
        negcm = -C * mn;
        lrun *= alpha;
#pragma unroll
        for (int dt = 0; dt < 2; ++dt) accO[dt] *= alpha;
      }

#pragma unroll
      for (int sub = 0; sub < 2; ++sub) {
        if (sub >= nsub) break;
#pragma unroll
        for (int i = 0; i < 16; ++i)
          p[sub * 16 + i] = fexp2(fmaf(p[sub * 16 + i], C, negcm));
      }
      float a[16];
#pragma unroll
      for (int i = 0; i < 16; ++i) a[i] = (nsub == 2) ? (p[i] + p[i + 16]) : p[i];
#pragma unroll
      for (int s = 8; s; s >>= 1)
#pragma unroll
        for (int i = 0; i < 8; ++i) if (i < s) a[i] += a[i + s];
      lrun += a[0] + __shfl_xor(a[0], 32, 64);

      s16x8 pf[4];
#pragma unroll
      for (int sub = 0; sub < 2; ++sub) {
        if (sub >= nsub) break;
#pragma unroll
        for (int hf = 0; hf < 2; ++hf) {
          const float* pp = &p[sub * 16 + hf * 8];
          unsigned X0 = cvtpk(pp[0], pp[1]);
          unsigned X1 = cvtpk(pp[2], pp[3]);
          unsigned Y0 = cvtpk(pp[4], pp[5]);
          unsigned Y1 = cvtpk(pp[6], pp[7]);
          asm volatile("v_permlane32_swap_b32 %0, %1" : "+v"(X0), "+v"(Y0));
          asm volatile("v_permlane32_swap_b32 %0, %1" : "+v"(X1), "+v"(Y1));
          union { unsigned u[4]; s16x8 v; } uu;
          uu.u[0] = X0; uu.u[1] = X1; uu.u[2] = Y0; uu.u[3] = Y1;
          pf[sub * 2 + hf] = uu.v;
        }
      }

      __builtin_amdgcn_s_setprio(1);
#pragma unroll
      for (int dt = 0; dt < 2; ++dt) {
        const int d = dt * 32 + l31;
        const int vswz = (d & 7) << 4;
#pragma unroll
        for (int kc = 0; kc < 4; ++kc) {
          if (kc >= nsub * 2) break;
          s16x8 vf = *reinterpret_cast<const s16x8*>(VsB + d * 128 + ((kc * 32 + hi * 16) ^ vswz));
          accO[dt] = __builtin_amdgcn_mfma_f32_32x32x16_bf16(vf, pf[kc], accO[dt], 0, 0, 0);
        }
      }
      __builtin_amdgcn_s_setprio(0);
    }
  }

  // ---- epilogue ----
  if (nseg == 1) {
    const int q = q0w + l31;
    const float inv = 1.0f / lrun;
#pragma unroll
    for (int dt = 0; dt < 2; ++dt)
#pragma unroll
      for (int rg = 0; rg < 4; ++rg) {
        int d0 = 8 * rg + 4 * hi + 32 * dt;
        ushort4 ov;
        ov.x = f2bf(accO[dt][rg * 4 + 0] * inv);
        ov.y = f2bf(accO[dt][rg * 4 + 1] * inv);
        ov.z = f2bf(accO[dt][rg * 4 + 2] * inv);
        ov.w = f2bf(accO[dt][rg * 4 + 3] * inv);
        *reinterpret_cast<ushort4*>(O + qbase + (size_t)q * DM + d0) = ov;
      }
  } else {
    const int pidx = (bh * 12 + (qi - 4)) * 4 + seg;
    float* op = Op + (size_t)pidx * (128 * 64);
    const int row = wid * 32 + l31;
#pragma unroll
    for (int dt = 0; dt < 2; ++dt)
#pragma unroll
      for (int rg = 0; rg < 4; ++rg) {
        int d0 = 8 * rg + 4 * hi + 32 * dt;
        f32x4 v4 = { accO[dt][rg * 4 + 0], accO[dt][rg * 4 + 1],
                     accO[dt][rg * 4 + 2], accO[dt][rg * 4 + 3] };
        *reinterpret_cast<f32x4*>(op + (size_t)row * 64 + d0) = v4;
      }
    if (hi == 0) {
      ml[(size_t)pidx * 256 + row * 2 + 0] = mrun;
      ml[(size_t)pidx * 256 + row * 2 + 1] = lrun;
    }
  }
}

// ---------------- merge split-KV partials (up to 4-way) ----------------
__global__ __launch_bounds__(256) void k_amerge(const float* __restrict__ Op,
                                                const float* __restrict__ ml,
                                                ushort* __restrict__ O) {
  const int bid = blockIdx.x;
  const int bh = bid / 12, qq = bid % 12;
  const int qi = qq + 4;
  const int nseg = (2 * qi + 9) >> 3;       // 2,3,4
  const int t = threadIdx.x;
  const int row = t >> 1, dh = (t & 1) * 32;
  const float C = 0.18033688011112043f;
  const int pbase = (bh * 12 + qq) * 4;

  float M = -1e30f;
  for (int s = 0; s < nseg; ++s)
    M = fmaxf(M, ml[(size_t)(pbase + s) * 256 + row * 2 + 0]);
  float wsum = 0.f;
  for (int s = 0; s < nseg; ++s) {
    float ms = ml[(size_t)(pbase + s) * 256 + row * 2 + 0];
    float ls = ml[(size_t)(pbase + s) * 256 + row * 2 + 1];
    wsum += ls * fexp2(C * (ms - M));
  }
  const float inv = 1.0f / wsum;

  f32x4 acc[8];
#pragma unroll
  for (int i = 0; i < 8; ++i) acc[i] = (f32x4){0.f, 0.f, 0.f, 0.f};
  for (int s = 0; s < nseg; ++s) {
    float wsc = fexp2(C * (ml[(size_t)(pbase + s) * 256 + row * 2 + 0] - M));
    const float* os = Op + (size_t)(pbase + s) * (128 * 64) + (size_t)row * 64 + dh;
#pragma unroll
    for (int i = 0; i < 8; ++i) {
      f32x4 v = reinterpret_cast<const f32x4*>(os)[i];
      acc[i] += v * wsc;
    }
  }

  const int b = bh >> 4, h = bh & 15;
  const int n = qi * 128 + row;
  ushort* dst = O + ((size_t)(b * NN + n)) * DM + h * DK + dh;
#pragma unroll
  for (int i = 0; i < 8; ++i) {
    ushort4 ov;
    ov.x = f2bf(acc[i][0] * inv);
    ov.y = f2bf(acc[i][1] * inv);
    ov.z = f2bf(acc[i][2] * inv);
    ov.w = f2bf(acc[i][3] * inv);
    reinterpret_cast<ushort4*>(dst)[i] = ov;
  }
}

// ---------------- launch ----------------
extern "C" void kernel_launch(void* const* d_in, const int* in_sizes, int n_in,
                              void* d_out, int out_size, void* d_ws, size_t ws_size,
                              hipStream_t stream) {
  const float* tgt = (const float*)d_in[0];
  const float* Wq  = (const float*)d_in[3];
  const float* Wk  = (const float*)d_in[4];
  const float* Wv  = (const float*)d_in[5];
  const float* Wo  = (const float*)d_in[6];
  const float* bo  = (const float*)d_in[7];
  const float* W1  = (const float*)d_in[8];
  const float* b1  = (const float*)d_in[9];
  const float* W2  = (const float*)d_in[10];
  const float* b2  = (const float*)d_in[11];
  const float* g1  = (const float*)d_in[12];
  const float* be1 = (const float*)d_in[13];
  const float* g2  = (const float*)d_in[14];
  const float* be2 = (const float*)d_in[15];

  char* ws = (char*)d_ws;
  size_t off = 0;
  auto alloc = [&](size_t bytes) {
    void* p = ws + off;
    off += (bytes + 255) & ~(size_t)255;
    return p;
  };
  ushort* xb   = (ushort*)alloc((size_t)ROWS * DM * 2);
  ushort* wqb  = (ushort*)alloc((size_t)DM * DM * 2);   // wq|wk|wv contiguous
  ushort* wkb  = (ushort*)alloc((size_t)DM * DM * 2);
  ushort* wvb  = (ushort*)alloc((size_t)DM * DM * 2);
  ushort* wob  = (ushort*)alloc((size_t)DM * DM * 2);
  ushort* w1b  = (ushort*)alloc((size_t)FF * DM * 2);
  ushort* w2b  = (ushort*)alloc((size_t)DM * FF * 2);
  ushort* qbuf = (ushort*)alloc((size_t)ROWS * DM * 2); // q|k|v|vT contiguous
  ushort* kbuf = (ushort*)alloc((size_t)ROWS * DM * 2);
  ushort* vbuf = (ushort*)alloc((size_t)ROWS * DM * 2); // unused (V fused to vT)
  ushort* vtb  = (ushort*)alloc((size_t)ROWS * DM * 2);
  ushort* atnb = (ushort*)alloc((size_t)ROWS * DM * 2);
  float*  h1   = (float*)alloc((size_t)ROWS * DM * 4);
  float*  x1f  = (float*)alloc((size_t)ROWS * DM * 4);  // kept for layout (unused)
  ushort* x1b  = (ushort*)alloc((size_t)ROWS * DM * 2);
  ushort* t1b  = (ushort*)alloc((size_t)ROWS * FF * 2);
  float*  mlb  = (float*)alloc((size_t)1536 * 256 * 4);      // m,l partials
  float*  Opb  = h1;            // attn O-partials overlay dead h1/x1f region
  float*  pp   = (float*)qbuf;  // FFN2 split-K partials overlay dead q/k/v/vT
  (void)ws_size; (void)in_sizes; (void)n_in; (void)out_size;
  (void)wkb; (void)wvb; (void)kbuf; (void)vbuf; (void)vtb; (void)x1f;

  dim3 blk(256);
  k_cast7<<<dim3(16384), blk, 0, stream>>>(tgt, Wq, Wk, Wv, Wo, W1, W2,
                                           xb, wqb, w1b, w2b);

  // fused QKV (K-third pre-swizzled; V-third fused transpose -> vtb)
  k_gemm<0, 128, true, 1><<<dim3(24 * 32), blk, 0, stream>>>(
      xb, wqb, nullptr, nullptr, qbuf, nullptr, DM, 24);

  k_attn<<<dim3(1280), blk, 0, stream>>>(qbuf, kbuf, vtb, atnb, Opb, mlb);
  k_amerge<<<dim3(384), blk, 0, stream>>>(Opb, mlb, atnb);

  // O-projection + bo + residual(xb, bf16) -> f32 h1 (overwrites dead partials)
  k_gemm<2, 64, false, 1><<<dim3(16 * 32), blk, 0, stream>>>(
      atnb, wob, bo, xb, nullptr, h1, DM, 16);
  // LN1: h1 -> x1b (bf16 only)
  k_ln<0><<<dim3(ROWS), blk, 0, stream>>>(h1, nullptr, nullptr, nullptr,
                                          g1, be1, nullptr, x1b);

  // FFN1
  k_gemm<1, 128, false, 1><<<dim3(32 * 32), blk, 0, stream>>>(
      x1b, w1b, b1, nullptr, t1b, nullptr, DM, 32);
  // FFN2: split-K=2, raw f32 partials into pp (q/k/v/vT region, now dead)
  k_gemm<3, 64, false, 2><<<dim3(2 * 16 * 32), blk, 0, stream>>>(
      t1b, w2b, nullptr, nullptr, nullptr, pp, FF, 16);
  // LN2: x1b(bf16) + split-K reduce + b2 -> d_out (f32)
  k_ln<1><<<dim3(ROWS), blk, 0, stream>>>(x1b, pp, pp + (size_t)ROWS * DM, b2,
                                          g2, be2, (float*)d_out, nullptr);
}

// Round 17
// 254.918 us; speedup vs baseline: 1.0369x; 1.0130x over previous
//
#include <hip/hip_runtime.h>

// CausalSALayer: post-norm transformer decoder layer on gfx950.
// B=2, N=2048, D=1024, H=16, dk=64, FFN=4096. bf16 MFMA compute, f32 accum.
// R14 base + T13 threshold-defer (attn) + bf16 split-K partials (FFN2).

#define DEV __device__ __forceinline__

typedef __attribute__((ext_vector_type(4)))  float f32x4;
typedef __attribute__((ext_vector_type(16))) float f32x16;
typedef __attribute__((ext_vector_type(8)))  short s16x8;

static constexpr int Bb   = 2;
static constexpr int NN   = 2048;
static constexpr int DM   = 1024;
static constexpr int HH   = 16;
static constexpr int DK   = 64;
static constexpr int FF   = 4096;
static constexpr int ROWS = Bb * NN;  // 4096

#define AS1(p) ((const __attribute__((address_space(1))) void*)(p))
#define AS3(p) ((__attribute__((address_space(3))) void*)(p))

DEV unsigned short f2bf(float f) {
  unsigned u = __float_as_uint(f);
  u += 0x7fff + ((u >> 16) & 1);   // RNE
  return (unsigned short)(u >> 16);
}
DEV float bf2f(unsigned short u) {
  return __uint_as_float((unsigned)u << 16);
}
DEV float fexp2(float x) {
  float r;
  asm("v_exp_f32 %0, %1" : "=v"(r) : "v"(x));
  return r;
}
DEV unsigned cvtpk(float lo, float hi) {
  unsigned r;
  asm("v_cvt_pk_bf16_f32 %0, %1, %2" : "=v"(r) : "v"(lo), "v"(hi));
  return r;
}

// ---------------- fused cast f32 -> bf16: all 7 tensors in one launch --------
__global__ __launch_bounds__(256) void k_cast7(
    const float* __restrict__ tgt, const float* __restrict__ Wq,
    const float* __restrict__ Wk, const float* __restrict__ Wv,
    const float* __restrict__ Wo, const float* __restrict__ W1,
    const float* __restrict__ W2,
    ushort* __restrict__ xb, ushort* __restrict__ wqb,
    ushort* __restrict__ w1b, ushort* __restrict__ w2b) {
  const int i = blockIdx.x * 256 + threadIdx.x;
  constexpr int S0 = 1048576;   // tgt float4s
  constexpr int S1 = 262144;    // per-DxD-weight float4s
  const float4* src;
  ushort* dstp;
  if (i < S0)               { src = (const float4*)tgt + i;            dstp = xb  + (size_t)i * 4; }
  else if (i < S0 + S1)     { src = (const float4*)Wq + (i - S0);      dstp = wqb + (size_t)(i - S0) * 4; }
  else if (i < S0 + 2 * S1) { src = (const float4*)Wk + (i - S0 - S1); dstp = wqb + (size_t)(i - S0) * 4; }
  else if (i < S0 + 3 * S1) { src = (const float4*)Wv + (i - S0 - 2 * S1); dstp = wqb + (size_t)(i - S0) * 4; }
  else if (i < S0 + 4 * S1) { src = (const float4*)Wo + (i - S0 - 3 * S1); dstp = wqb + (size_t)(i - S0) * 4; }
  else if (i < 3 * S0)      { src = (const float4*)W1 + (i - 2 * S0);  dstp = w1b + (size_t)(i - 2 * S0) * 4; }
  else                      { src = (const float4*)W2 + (i - 3 * S0);  dstp = w2b + (size_t)(i - 3 * S0) * 4; }
  float4 v = *src;
  ushort4 o;
  o.x = f2bf(v.x); o.y = f2bf(v.y); o.z = f2bf(v.z); o.w = f2bf(v.w);
  *reinterpret_cast<ushort4*>(dstp) = o;
}

// ---------------- GEMM: double-buffer, counted-vmcnt pipeline (T3/T4) ------------
// EPI 0: C->bf16 ; 1: C+bias,gelu->bf16 ; 2: C+bias+resid(bf16)->f32 ;
// EPI 3: raw bf16 partial (split-K).
// QKV: outputs to q|k contig; K-third pre-swizzled; V-third fused transpose->vT.
template <int EPI, int BN, bool QKV, int SPLITK>
__global__ __launch_bounds__(256) void k_gemm(
    const ushort* __restrict__ A, const ushort* __restrict__ Bt,
    const float* __restrict__ bias, const ushort* __restrict__ resid,
    ushort* __restrict__ Cb, float* __restrict__ Cf,
    int K, int nbx) {
  __shared__ ushort As[2][128][32];
  __shared__ ushort Bs[2][BN][32];

  const int t = threadIdx.x;
  const int lane = t & 63, w = t >> 6;
  const int lr = lane & 15, lg = lane >> 4;
  const int lrow = lane >> 2, lc8 = (lane & 3) * 8;

  const int nwg = gridDim.x;
  const int bid = blockIdx.x;
  const int q8 = nwg >> 3, r8 = nwg & 7;
  const int xcd = bid & 7, lin = bid >> 3;
  int wg = (xcd < r8 ? xcd * (q8 + 1) : r8 * (q8 + 1) + (xcd - r8) * q8) + lin;
  int kc = 0;
  if constexpr (SPLITK == 2) { kc = wg & 1; wg >>= 1; }
  const int band = wg / (4 * nbx);
  const int inn  = wg % (4 * nbx);
  const int by = band * 4 + (inn & 3);
  const int bx = inn >> 2;

  const int bRow = by * 128;
  const int bCol = bx * BN;
  const int Kc = K / SPLITK;
  const int kofs = kc * Kc;
  const int nk = Kc / 32;

  constexpr int NW = BN / 32;
  const int wRow = (w >> 1) * 64, wCol = (w & 1) * (BN / 2);

  f32x4 acc[4][NW];
#pragma unroll
  for (int m = 0; m < 4; ++m)
#pragma unroll
    for (int n = 0; n < NW; ++n) acc[m][n] = (f32x4){0.f, 0.f, 0.f, 0.f};

  auto stage = [&](int buf, int tile) {
    const int kb = kofs + tile * 32;
#pragma unroll
    for (int i = 0; i < 2; ++i) {
      int rr = w * 32 + i * 16;
      __builtin_amdgcn_global_load_lds(
          AS1(A + (size_t)(bRow + rr + lrow) * K + kb + lc8),
          AS3(&As[buf][rr][0]), 16, 0, 0);
    }
#pragma unroll
    for (int i = 0; i < BN / 64; ++i) {
      int rr = w * (BN / 4) + i * 16;
      __builtin_amdgcn_global_load_lds(
          AS1(Bt + (size_t)(bCol + rr + lrow) * K + kb + lc8),
          AS3(&Bs[buf][rr][0]), 16, 0, 0);
    }
  };

  stage(0, 0);
  for (int tt = 0; tt < nk; ++tt) {
    const int cur = tt & 1;
    if (tt + 1 < nk) {
      stage(cur ^ 1, tt + 1);   // buffer read at tt-1; safe after its trailing barrier
      if constexpr (BN == 128) asm volatile("s_waitcnt vmcnt(4)" ::: "memory");
      else                     asm volatile("s_waitcnt vmcnt(3)" ::: "memory");
    } else {
      asm volatile("s_waitcnt vmcnt(0)" ::: "memory");
    }
    __builtin_amdgcn_s_barrier();
    __builtin_amdgcn_sched_barrier(0);

    s16x8 af[4], bfr[NW];
#pragma unroll
    for (int m = 0; m < 4; ++m)
      af[m] = *reinterpret_cast<const s16x8*>(&As[cur][wRow + m * 16 + lr][lg * 8]);
#pragma unroll
    for (int n = 0; n < NW; ++n)
      bfr[n] = *reinterpret_cast<const s16x8*>(&Bs[cur][wCol + n * 16 + lr][lg * 8]);
#pragma unroll
    for (int m = 0; m < 4; ++m)
#pragma unroll
      for (int n = 0; n < NW; ++n)
        acc[m][n] = __builtin_amdgcn_mfma_f32_16x16x32_bf16(af[m], bfr[n], acc[m][n], 0, 0, 0);

    asm volatile("s_waitcnt lgkmcnt(0)" ::: "memory");
    __builtin_amdgcn_s_barrier();
    __builtin_amdgcn_sched_barrier(0);
  }

  // ---- epilogue ----
  ushort* CbOut = Cb;
  int colBase = bCol, Ncols = nbx * BN, third = 0;
  if (QKV) {
    third = bCol >> 10;
    CbOut = Cb + (size_t)third * ROWS * DM;
    colBase = bCol & 1023;
    Ncols = DM;
  }
#pragma unroll
  for (int m = 0; m < 4; ++m) {
    int gr = bRow + wRow + m * 16 + lg * 4;
#pragma unroll
    for (int n = 0; n < NW; ++n) {
      int gc = colBase + wCol + n * 16 + lr;
      if (QKV && third == 2) {
        // V-third: fused transpose to vT[bh][d][n], 8-chunk swizzled
        int h = gc >> 6, d = gc & 63;
        int b = gr >> 11, ntok = gr & (NN - 1);
        size_t basev = ((size_t)(b * HH + h) * DK + d) * NN;
        int nb = ntok & ~63, c = (ntok >> 3) & 7, j0 = ntok & 7;
        ushort4 ov;
        ov.x = f2bf(acc[m][n][0]);
        ov.y = f2bf(acc[m][n][1]);
        ov.z = f2bf(acc[m][n][2]);
        ov.w = f2bf(acc[m][n][3]);
        ushort* VT = Cb + (size_t)3 * ROWS * DM;   // vtb region
        *reinterpret_cast<ushort4*>(VT + basev + nb + ((c ^ (d & 7)) << 3) + j0) = ov;
        continue;
      }
      float bv = (EPI == 1 || EPI == 2) ? bias[gc] : 0.0f;
#pragma unroll
      for (int r = 0; r < 4; ++r) {
        int nr = gr + r;
        float v = acc[m][n][r] + bv;
        if (EPI == 3) {
          Cb[((size_t)kc * ROWS + nr) * Ncols + gc] = f2bf(v);   // bf16 partial
        } else if (EPI == 2) {
          size_t idx = (size_t)nr * Ncols + gc;
          Cf[idx] = v + bf2f(resid[idx]);
        } else if (EPI == 1) {
          size_t idx = (size_t)nr * Ncols + gc;
          float u = v + 0.044715f * v * v * v;
          float g = v / (1.0f + __expf(-1.5957691216057308f * u));
          CbOut[idx] = f2bf(g);
        } else {
          int gcs = gc;
          if (QKV && third == 1)   // pre-swizzle K rows for attn's linear gload_lds
            gcs = (gc & ~63) | ((gc ^ ((nr & 7) << 3)) & 63);
          CbOut[(size_t)nr * Ncols + gcs] = f2bf(v);
        }
      }
    }
  }
}

// ---------------- LayerNorm over D=1024 rows ----------------
// MODE 0: in f32 -> outb bf16 only (LN1).
// MODE 1: in bf16 + p0 + p1 (bf16 split-K partials) + pb reduce -> outf f32 (LN2).
template <int MODE>
__global__ __launch_bounds__(256) void k_ln(const void* __restrict__ inp,
                                            const ushort* __restrict__ p0,
                                            const ushort* __restrict__ p1,
                                            const float* __restrict__ pb,
                                            const float* __restrict__ g,
                                            const float* __restrict__ bta,
                                            float* __restrict__ outf,
                                            ushort* __restrict__ outb) {
  const int row = blockIdx.x;
  const int t = threadIdx.x;
  float4 v;
  if (MODE == 0) {
    v = reinterpret_cast<const float4*>((const float*)inp + (size_t)row * DM)[t];
  } else {
    ushort4 xv = reinterpret_cast<const ushort4*>((const ushort*)inp + (size_t)row * DM)[t];
    ushort4 a = reinterpret_cast<const ushort4*>(p0 + (size_t)row * DM)[t];
    ushort4 b = reinterpret_cast<const ushort4*>(p1 + (size_t)row * DM)[t];
    float4 c = reinterpret_cast<const float4*>(pb)[t];
    v.x = bf2f(xv.x) + bf2f(a.x) + bf2f(b.x) + c.x;
    v.y = bf2f(xv.y) + bf2f(a.y) + bf2f(b.y) + c.y;
    v.z = bf2f(xv.z) + bf2f(a.z) + bf2f(b.z) + c.z;
    v.w = bf2f(xv.w) + bf2f(a.w) + bf2f(b.w) + c.w;
  }
  float s1 = v.x + v.y + v.z + v.w;
  float s2 = v.x * v.x + v.y * v.y + v.z * v.z + v.w * v.w;
#pragma unroll
  for (int m = 32; m; m >>= 1) {
    s1 += __shfl_xor(s1, m, 64);
    s2 += __shfl_xor(s2, m, 64);
  }
  __shared__ float red[2][4];
  if ((t & 63) == 0) { red[0][t >> 6] = s1; red[1][t >> 6] = s2; }
  __syncthreads();
  s1 = red[0][0] + red[0][1] + red[0][2] + red[0][3];
  s2 = red[1][0] + red[1][1] + red[1][2] + red[1][3];
  const float mu = s1 * (1.0f / DM);
  const float var = s2 * (1.0f / DM) - mu * mu;
  const float rstd = rsqrtf(var + 1e-5f);
  float4 gv = reinterpret_cast<const float4*>(g)[t];
  float4 bv = reinterpret_cast<const float4*>(bta)[t];
  float4 o;
  o.x = (v.x - mu) * rstd * gv.x + bv.x;
  o.y = (v.y - mu) * rstd * gv.y + bv.y;
  o.z = (v.z - mu) * rstd * gv.z + bv.z;
  o.w = (v.w - mu) * rstd * gv.w + bv.w;
  if (MODE == 1) {
    reinterpret_cast<float4*>(outf + (size_t)row * DM)[t] = o;
  } else {
    ushort4 ob;
    ob.x = f2bf(o.x); ob.y = f2bf(o.y); ob.z = f2bf(o.z); ob.w = f2bf(o.w);
    reinterpret_cast<ushort4*>(outb + (size_t)row * DM)[t] = ob;
  }
}

// ---------------- causal flash attention: XCD-pinned, <=8-tile segments ----
static __device__ const unsigned char SCHED40[40][2] = {
  {15,0},{15,1},{15,2},{15,3}, {14,0},{14,1},{14,2},{14,3},
  {13,0},{13,1},{13,2},{13,3}, {12,0},{12,1},{12,2},{12,3},
  {11,0},{11,1},{11,2}, {10,0},{10,1},{10,2},
  {9,0},{9,1},{9,2}, {8,0},{8,1},{8,2},
  {7,0},{7,1}, {6,0},{6,1}, {5,0},{5,1}, {4,0},{4,1},
  {3,0},{2,0},{1,0},{0,0}};

__global__ __launch_bounds__(256) void k_attn(const ushort* __restrict__ Q,
                                              const ushort* __restrict__ Kb,
                                              const ushort* __restrict__ vT,
                                              ushort* __restrict__ O,
                                              float* __restrict__ Op,
                                              float* __restrict__ ml) {
  __shared__ ushort Ks[2][64 * 64];
  __shared__ ushort Vs[2][64 * 64];

  const int t = threadIdx.x;
  const int bid = blockIdx.x;
  const int xcd = bid & 7, j = bid >> 3;    // j in [0,160)
  const int head = j & 3, e = j >> 2;       // e in [0,40)
  const int qi = SCHED40[e][0], seg = SCHED40[e][1];
  const int bh = xcd * 4 + head;
  const int ntiles = 2 * qi + 2;
  const int nseg = (2 * qi + 9) >> 3;       // 1,2,3,4
  const int tb = ntiles / nseg, rem = ntiles % nseg;
  const int kt0 = seg * tb + (seg < rem ? seg : rem);
  const int kt1 = kt0 + tb + (seg < rem ? 1 : 0);

  const int lane = t & 63, wid = t >> 6;
  const int l31 = lane & 31, hi = lane >> 5;
  const int q0w = qi * 128 + wid * 32;
  const size_t qbase = ((size_t)(bh >> 4) * NN) * DM + (bh & 15) * DK;
  const size_t vbase = (size_t)bh * DK * NN;

  const float C = 0.18033688011112043f;   // 0.125 * log2(e)
  const float THR = 44.3614195558365f;    // 8 / C: defer-rescale threshold (T13)

  s16x8 qf[4];
#pragma unroll
  for (int c = 0; c < 4; ++c)
    qf[c] = *reinterpret_cast<const s16x8*>(Q + qbase + (size_t)(q0w + l31) * DM + c * 16 + hi * 8);

  float mrun = -1e30f, lrun = 0.f, negcm = 1e30f;
  f32x16 accO[2];
#pragma unroll
  for (int dt = 0; dt < 2; ++dt)
#pragma unroll
    for (int r = 0; r < 16; ++r) accO[dt][r] = 0.f;

  auto stage = [&](int buf, int kt) {
    const int kk = kt * 64;
#pragma unroll
    for (int i = 0; i < 2; ++i) {
      int row0 = wid * 16 + i * 8;
      __builtin_amdgcn_global_load_lds(
          AS1(Kb + qbase + (size_t)(kk + row0 + (lane >> 3)) * DM + (lane & 7) * 8),
          AS3(&Ks[buf][row0 * 64]), 16, 0, 0);
      __builtin_amdgcn_global_load_lds(
          AS1(vT + vbase + (size_t)(row0 + (lane >> 3)) * NN + kk + (lane & 7) * 8),
          AS3(&Vs[buf][row0 * 64]), 16, 0, 0);
    }
  };

  stage(0, kt0);
  for (int kt = kt0, li = 0; kt < kt1; ++kt, ++li) {
    const int cur = li & 1;
    const int kk = kt * 64;
    __syncthreads();
    if (kt + 1 < kt1) stage(cur ^ 1, kt + 1);

    if (kk <= q0w + 31) {
      const char* KsB = (const char*)Ks[cur];
      const char* VsB = (const char*)Vs[cur];
      const bool diag = (kk + 64 > q0w);
      const int nsub = (kk + 32 <= q0w + 31) ? 2 : 1;   // wave-uniform

      f32x16 st[2];
      __builtin_amdgcn_s_setprio(1);
#pragma unroll
      for (int sub = 0; sub < 2; ++sub) {
        if (sub >= nsub) break;
#pragma unroll
        for (int r = 0; r < 16; ++r) st[sub][r] = 0.f;
        const int row = sub * 32 + l31;
        const int swz = (row & 7) << 4;
#pragma unroll
        for (int c = 0; c < 4; ++c) {
          s16x8 kf = *reinterpret_cast<const s16x8*>(KsB + row * 128 + ((c * 32 + hi * 16) ^ swz));
          st[sub] = __builtin_amdgcn_mfma_f32_32x32x16_bf16(kf, qf[c], st[sub], 0, 0, 0);
        }
      }
      __builtin_amdgcn_s_setprio(0);

      const int q = q0w + l31;
      float p[32];
#pragma unroll
      for (int sub = 0; sub < 2; ++sub) {
        if (sub >= nsub) break;
#pragma unroll
        for (int r = 0; r < 16; ++r) {
          float v = st[sub][r];
          if (diag) {
            int kl = sub * 32 + (r & 3) + 8 * (r >> 2) + 4 * hi;
            if (kk + kl > q) v = -1e30f;
          }
          p[sub * 16 + r] = v;
        }
      }
      float m8[8];
#pragma unroll
      for (int i = 0; i < 8; ++i) {
        float x = fmaxf(p[i], p[i + 8]);
        if (nsub == 2) x = fmaxf(fmaxf(p[i + 16], p[i + 24]), x);
        m8[i] = x;
      }
      float rm = fmaxf(fmaxf(fmaxf(m8[0], m8[1]), fmaxf(m8[2], m8[3])),
                       fmaxf(fmaxf(m8[4], m8[5]), fmaxf(m8[6], m8[7])));
      rm = fmaxf(rm, __shfl_xor(rm, 32, 64));

      // T13 defer-rescale: only rescale when the max grows past THR (P <= 2^8)
      if (__any(rm > mrun + THR)) {
        const float mn = fmaxf(mrun, rm);
        const float alpha = fexp2(C * (mrun - mn));
        mrun = mn;
        negcm = -C * mn;
        lrun *= alpha;
#pragma unroll
        for (int dt = 0; dt < 2; ++dt) accO[dt] *= alpha;
      }

#pragma unroll
      for (int sub = 0; sub < 2; ++sub) {
        if (sub >= nsub) break;
#pragma unroll
        for (int i = 0; i < 16; ++i)
          p[sub * 16 + i] = fexp2(fmaf(p[sub * 16 + i], C, negcm));
      }
      float a[16];
#pragma unroll
      for (int i = 0; i < 16; ++i) a[i] = (nsub == 2) ? (p[i] + p[i + 16]) : p[i];
#pragma unroll
      for (int s = 8; s; s >>= 1)
#pragma unroll
        for (int i = 0; i < 8; ++i) if (i < s) a[i] += a[i + s];
      lrun += a[0] + __shfl_xor(a[0], 32, 64);

      s16x8 pf[4];
#pragma unroll
      for (int sub = 0; sub < 2; ++sub) {
        if (sub >= nsub) break;
#pragma unroll
        for (int hf = 0; hf < 2; ++hf) {
          const float* pp = &p[sub * 16 + hf * 8];
          unsigned X0 = cvtpk(pp[0], pp[1]);
          unsigned X1 = cvtpk(pp[2], pp[3]);
          unsigned Y0 = cvtpk(pp[4], pp[5]);
          unsigned Y1 = cvtpk(pp[6], pp[7]);
          asm volatile("v_permlane32_swap_b32 %0, %1" : "+v"(X0), "+v"(Y0));
          asm volatile("v_permlane32_swap_b32 %0, %1" : "+v"(X1), "+v"(Y1));
          union { unsigned u[4]; s16x8 v; } uu;
          uu.u[0] = X0; uu.u[1] = X1; uu.u[2] = Y0; uu.u[3] = Y1;
          pf[sub * 2 + hf] = uu.v;
        }
      }

      __builtin_amdgcn_s_setprio(1);
#pragma unroll
      for (int dt = 0; dt < 2; ++dt) {
        const int d = dt * 32 + l31;
        const int vswz = (d & 7) << 4;
#pragma unroll
        for (int kc = 0; kc < 4; ++kc) {
          if (kc >= nsub * 2) break;
          s16x8 vf = *reinterpret_cast<const s16x8*>(VsB + d * 128 + ((kc * 32 + hi * 16) ^ vswz));
          accO[dt] = __builtin_amdgcn_mfma_f32_32x32x16_bf16(vf, pf[kc], accO[dt], 0, 0, 0);
        }
      }
      __builtin_amdgcn_s_setprio(0);
    }
  }

  // ---- epilogue ----
  if (nseg == 1) {
    const int q = q0w + l31;
    const float inv = 1.0f / lrun;
#pragma unroll
    for (int dt = 0; dt < 2; ++dt)
#pragma unroll
      for (int rg = 0; rg < 4; ++rg) {
        int d0 = 8 * rg + 4 * hi + 32 * dt;
        ushort4 ov;
        ov.x = f2bf(accO[dt][rg * 4 + 0] * inv);
        ov.y = f2bf(accO[dt][rg * 4 + 1] * inv);
        ov.z = f2bf(accO[dt][rg * 4 + 2] * inv);
        ov.w = f2bf(accO[dt][rg * 4 + 3] * inv);
        *reinterpret_cast<ushort4*>(O + qbase + (size_t)q * DM + d0) = ov;
      }
  } else {
    const int pidx = (bh * 12 + (qi - 4)) * 4 + seg;
    float* op = Op + (size_t)pidx * (128 * 64);
    const int row = wid * 32 + l31;
#pragma unroll
    for (int dt = 0; dt < 2; ++dt)
#pragma unroll
      for (int rg = 0; rg < 4; ++rg) {
        int d0 = 8 * rg + 4 * hi + 32 * dt;
        f32x4 v4 = { accO[dt][rg * 4 + 0], accO[dt][rg * 4 + 1],
                     accO[dt][rg * 4 + 2], accO[dt][rg * 4 + 3] };
        *reinterpret_cast<f32x4*>(op + (size_t)row * 64 + d0) = v4;
      }
    if (hi == 0) {
      ml[(size_t)pidx * 256 + row * 2 + 0] = mrun;
      ml[(size_t)pidx * 256 + row * 2 + 1] = lrun;
    }
  }
}

// ---------------- merge split-KV partials (up to 4-way) ----------------
__global__ __launch_bounds__(256) void k_amerge(const float* __restrict__ Op,
                                                const float* __restrict__ ml,
                                                ushort* __restrict__ O) {
  const int bid = blockIdx.x;
  const int bh = bid / 12, qq = bid % 12;
  const int qi = qq + 4;
  const int nseg = (2 * qi + 9) >> 3;       // 2,3,4
  const int t = threadIdx.x;
  const int row = t >> 1, dh = (t & 1) * 32;
  const float C = 0.18033688011112043f;
  const int pbase = (bh * 12 + qq) * 4;

  float M = -1e30f;
  for (int s = 0; s < nseg; ++s)
    M = fmaxf(M, ml[(size_t)(pbase + s) * 256 + row * 2 + 0]);
  float wsum = 0.f;
  for (int s = 0; s < nseg; ++s) {
    float ms = ml[(size_t)(pbase + s) * 256 + row * 2 + 0];
    float ls = ml[(size_t)(pbase + s) * 256 + row * 2 + 1];
    wsum += ls * fexp2(C * (ms - M));
  }
  const float inv = 1.0f / wsum;

  f32x4 acc[8];
#pragma unroll
  for (int i = 0; i < 8; ++i) acc[i] = (f32x4){0.f, 0.f, 0.f, 0.f};
  for (int s = 0; s < nseg; ++s) {
    float wsc = fexp2(C * (ml[(size_t)(pbase + s) * 256 + row * 2 + 0] - M));
    const float* os = Op + (size_t)(pbase + s) * (128 * 64) + (size_t)row * 64 + dh;
#pragma unroll
    for (int i = 0; i < 8; ++i) {
      f32x4 v = reinterpret_cast<const f32x4*>(os)[i];
      acc[i] += v * wsc;
    }
  }

  const int b = bh >> 4, h = bh & 15;
  const int n = qi * 128 + row;
  ushort* dst = O + ((size_t)(b * NN + n)) * DM + h * DK + dh;
#pragma unroll
  for (int i = 0; i < 8; ++i) {
    ushort4 ov;
    ov.x = f2bf(acc[i][0] * inv);
    ov.y = f2bf(acc[i][1] * inv);
    ov.z = f2bf(acc[i][2] * inv);
    ov.w = f2bf(acc[i][3] * inv);
    reinterpret_cast<ushort4*>(dst)[i] = ov;
  }
}

// ---------------- launch ----------------
extern "C" void kernel_launch(void* const* d_in, const int* in_sizes, int n_in,
                              void* d_out, int out_size, void* d_ws, size_t ws_size,
                              hipStream_t stream) {
  const float* tgt = (const float*)d_in[0];
  const float* Wq  = (const float*)d_in[3];
  const float* Wk  = (const float*)d_in[4];
  const float* Wv  = (const float*)d_in[5];
  const float* Wo  = (const float*)d_in[6];
  const float* bo  = (const float*)d_in[7];
  const float* W1  = (const float*)d_in[8];
  const float* b1  = (const float*)d_in[9];
  const float* W2  = (const float*)d_in[10];
  const float* b2  = (const float*)d_in[11];
  const float* g1  = (const float*)d_in[12];
  const float* be1 = (const float*)d_in[13];
  const float* g2  = (const float*)d_in[14];
  const float* be2 = (const float*)d_in[15];

  char* ws = (char*)d_ws;
  size_t off = 0;
  auto alloc = [&](size_t bytes) {
    void* p = ws + off;
    off += (bytes + 255) & ~(size_t)255;
    return p;
  };
  ushort* xb   = (ushort*)alloc((size_t)ROWS * DM * 2);
  ushort* wqb  = (ushort*)alloc((size_t)DM * DM * 2);   // wq|wk|wv contiguous
  ushort* wkb  = (ushort*)alloc((size_t)DM * DM * 2);
  ushort* wvb  = (ushort*)alloc((size_t)DM * DM * 2);
  ushort* wob  = (ushort*)alloc((size_t)DM * DM * 2);
  ushort* w1b  = (ushort*)alloc((size_t)FF * DM * 2);
  ushort* w2b  = (ushort*)alloc((size_t)DM * FF * 2);
  ushort* qbuf = (ushort*)alloc((size_t)ROWS * DM * 2); // q|k|v|vT contiguous
  ushort* kbuf = (ushort*)alloc((size_t)ROWS * DM * 2);
  ushort* vbuf = (ushort*)alloc((size_t)ROWS * DM * 2); // unused (V fused to vT)
  ushort* vtb  = (ushort*)alloc((size_t)ROWS * DM * 2);
  ushort* atnb = (ushort*)alloc((size_t)ROWS * DM * 2);
  float*  h1   = (float*)alloc((size_t)ROWS * DM * 4);
  float*  x1f  = (float*)alloc((size_t)ROWS * DM * 4);  // kept for layout (unused)
  ushort* x1b  = (ushort*)alloc((size_t)ROWS * DM * 2);
  ushort* t1b  = (ushort*)alloc((size_t)ROWS * FF * 2);
  float*  mlb  = (float*)alloc((size_t)1536 * 256 * 4);      // m,l partials
  float*  Opb  = h1;             // attn O-partials overlay dead h1/x1f region
  ushort* ppb  = (ushort*)qbuf;  // FFN2 bf16 split-K partials overlay dead q/k
  (void)ws_size; (void)in_sizes; (void)n_in; (void)out_size;
  (void)wkb; (void)wvb; (void)kbuf; (void)vbuf; (void)vtb; (void)x1f;

  dim3 blk(256);
  k_cast7<<<dim3(16384), blk, 0, stream>>>(tgt, Wq, Wk, Wv, Wo, W1, W2,
                                           xb, wqb, w1b, w2b);

  // fused QKV (K-third pre-swizzled; V-third fused transpose -> vtb)
  k_gemm<0, 128, true, 1><<<dim3(24 * 32), blk, 0, stream>>>(
      xb, wqb, nullptr, nullptr, qbuf, nullptr, DM, 24);

  k_attn<<<dim3(1280), blk, 0, stream>>>(qbuf, kbuf, vtb, atnb, Opb, mlb);
  k_amerge<<<dim3(384), blk, 0, stream>>>(Opb, mlb, atnb);

  // O-projection + bo + residual(xb, bf16) -> f32 h1 (overwrites dead partials)
  k_gemm<2, 64, false, 1><<<dim3(16 * 32), blk, 0, stream>>>(
      atnb, wob, bo, xb, nullptr, h1, DM, 16);
  // LN1: h1 -> x1b (bf16 only)
  k_ln<0><<<dim3(ROWS), blk, 0, stream>>>(h1, nullptr, nullptr, nullptr,
                                          g1, be1, nullptr, x1b);

  // FFN1
  k_gemm<1, 128, false, 1><<<dim3(32 * 32), blk, 0, stream>>>(
      x1b, w1b, b1, nullptr, t1b, nullptr, DM, 32);
  // FFN2: split-K=2, bf16 partials into ppb (q/k region, now dead)
  k_gemm<3, 64, false, 2><<<dim3(2 * 16 * 32), blk, 0, stream>>>(
      t1b, w2b, nullptr, nullptr, ppb, nullptr, FF, 16);
  // LN2: x1b(bf16) + bf16 split-K reduce + b2 -> d_out (f32)
  k_ln<1><<<dim3(ROWS), blk, 0, stream>>>(x1b, ppb, ppb + (size_t)ROWS * DM, b2,
                                          g2, be2, (float*)d_out, nullptr);
}

// Round 18
// 254.405 us; speedup vs baseline: 1.0389x; 1.0020x over previous
//
#include <hip/hip_runtime.h>

// CausalSALayer: post-norm transformer decoder layer on gfx950.
// B=2, N=2048, D=1024, H=16, dk=64, FFN=4096. bf16 MFMA compute, f32 accum.
// R17 base + deferred lrun reduction in attn (per-tile tree -> once at end).

#define DEV __device__ __forceinline__

typedef __attribute__((ext_vector_type(4)))  float f32x4;
typedef __attribute__((ext_vector_type(16))) float f32x16;
typedef __attribute__((ext_vector_type(8)))  short s16x8;

static constexpr int Bb   = 2;
static constexpr int NN   = 2048;
static constexpr int DM   = 1024;
static constexpr int HH   = 16;
static constexpr int DK   = 64;
static constexpr int FF   = 4096;
static constexpr int ROWS = Bb * NN;  // 4096

#define AS1(p) ((const __attribute__((address_space(1))) void*)(p))
#define AS3(p) ((__attribute__((address_space(3))) void*)(p))

DEV unsigned short f2bf(float f) {
  unsigned u = __float_as_uint(f);
  u += 0x7fff + ((u >> 16) & 1);   // RNE
  return (unsigned short)(u >> 16);
}
DEV float bf2f(unsigned short u) {
  return __uint_as_float((unsigned)u << 16);
}
DEV float fexp2(float x) {
  float r;
  asm("v_exp_f32 %0, %1" : "=v"(r) : "v"(x));
  return r;
}
DEV unsigned cvtpk(float lo, float hi) {
  unsigned r;
  asm("v_cvt_pk_bf16_f32 %0, %1, %2" : "=v"(r) : "v"(lo), "v"(hi));
  return r;
}

// ---------------- fused cast f32 -> bf16: all 7 tensors in one launch --------
__global__ __launch_bounds__(256) void k_cast7(
    const float* __restrict__ tgt, const float* __restrict__ Wq,
    const float* __restrict__ Wk, const float* __restrict__ Wv,
    const float* __restrict__ Wo, const float* __restrict__ W1,
    const float* __restrict__ W2,
    ushort* __restrict__ xb, ushort* __restrict__ wqb,
    ushort* __restrict__ w1b, ushort* __restrict__ w2b) {
  const int i = blockIdx.x * 256 + threadIdx.x;
  constexpr int S0 = 1048576;   // tgt float4s
  constexpr int S1 = 262144;    // per-DxD-weight float4s
  const float4* src;
  ushort* dstp;
  if (i < S0)               { src = (const float4*)tgt + i;            dstp = xb  + (size_t)i * 4; }
  else if (i < S0 + S1)     { src = (const float4*)Wq + (i - S0);      dstp = wqb + (size_t)(i - S0) * 4; }
  else if (i < S0 + 2 * S1) { src = (const float4*)Wk + (i - S0 - S1); dstp = wqb + (size_t)(i - S0) * 4; }
  else if (i < S0 + 3 * S1) { src = (const float4*)Wv + (i - S0 - 2 * S1); dstp = wqb + (size_t)(i - S0) * 4; }
  else if (i < S0 + 4 * S1) { src = (const float4*)Wo + (i - S0 - 3 * S1); dstp = wqb + (size_t)(i - S0) * 4; }
  else if (i < 3 * S0)      { src = (const float4*)W1 + (i - 2 * S0);  dstp = w1b + (size_t)(i - 2 * S0) * 4; }
  else                      { src = (const float4*)W2 + (i - 3 * S0);  dstp = w2b + (size_t)(i - 3 * S0) * 4; }
  float4 v = *src;
  ushort4 o;
  o.x = f2bf(v.x); o.y = f2bf(v.y); o.z = f2bf(v.z); o.w = f2bf(v.w);
  *reinterpret_cast<ushort4*>(dstp) = o;
}

// ---------------- GEMM: double-buffer, counted-vmcnt pipeline (T3/T4) ------------
// EPI 0: C->bf16 ; 1: C+bias,gelu->bf16 ; 2: C+bias+resid(bf16)->f32 ;
// EPI 3: raw bf16 partial (split-K).
// QKV: outputs to q|k contig; K-third pre-swizzled; V-third fused transpose->vT.
template <int EPI, int BN, bool QKV, int SPLITK>
__global__ __launch_bounds__(256) void k_gemm(
    const ushort* __restrict__ A, const ushort* __restrict__ Bt,
    const float* __restrict__ bias, const ushort* __restrict__ resid,
    ushort* __restrict__ Cb, float* __restrict__ Cf,
    int K, int nbx) {
  __shared__ ushort As[2][128][32];
  __shared__ ushort Bs[2][BN][32];

  const int t = threadIdx.x;
  const int lane = t & 63, w = t >> 6;
  const int lr = lane & 15, lg = lane >> 4;
  const int lrow = lane >> 2, lc8 = (lane & 3) * 8;

  const int nwg = gridDim.x;
  const int bid = blockIdx.x;
  const int q8 = nwg >> 3, r8 = nwg & 7;
  const int xcd = bid & 7, lin = bid >> 3;
  int wg = (xcd < r8 ? xcd * (q8 + 1) : r8 * (q8 + 1) + (xcd - r8) * q8) + lin;
  int kc = 0;
  if constexpr (SPLITK == 2) { kc = wg & 1; wg >>= 1; }
  const int band = wg / (4 * nbx);
  const int inn  = wg % (4 * nbx);
  const int by = band * 4 + (inn & 3);
  const int bx = inn >> 2;

  const int bRow = by * 128;
  const int bCol = bx * BN;
  const int Kc = K / SPLITK;
  const int kofs = kc * Kc;
  const int nk = Kc / 32;

  constexpr int NW = BN / 32;
  const int wRow = (w >> 1) * 64, wCol = (w & 1) * (BN / 2);

  f32x4 acc[4][NW];
#pragma unroll
  for (int m = 0; m < 4; ++m)
#pragma unroll
    for (int n = 0; n < NW; ++n) acc[m][n] = (f32x4){0.f, 0.f, 0.f, 0.f};

  auto stage = [&](int buf, int tile) {
    const int kb = kofs + tile * 32;
#pragma unroll
    for (int i = 0; i < 2; ++i) {
      int rr = w * 32 + i * 16;
      __builtin_amdgcn_global_load_lds(
          AS1(A + (size_t)(bRow + rr + lrow) * K + kb + lc8),
          AS3(&As[buf][rr][0]), 16, 0, 0);
    }
#pragma unroll
    for (int i = 0; i < BN / 64; ++i) {
      int rr = w * (BN / 4) + i * 16;
      __builtin_amdgcn_global_load_lds(
          AS1(Bt + (size_t)(bCol + rr + lrow) * K + kb + lc8),
          AS3(&Bs[buf][rr][0]), 16, 0, 0);
    }
  };

  stage(0, 0);
  for (int tt = 0; tt < nk; ++tt) {
    const int cur = tt & 1;
    if (tt + 1 < nk) {
      stage(cur ^ 1, tt + 1);   // buffer read at tt-1; safe after its trailing barrier
      if constexpr (BN == 128) asm volatile("s_waitcnt vmcnt(4)" ::: "memory");
      else                     asm volatile("s_waitcnt vmcnt(3)" ::: "memory");
    } else {
      asm volatile("s_waitcnt vmcnt(0)" ::: "memory");
    }
    __builtin_amdgcn_s_barrier();
    __builtin_amdgcn_sched_barrier(0);

    s16x8 af[4], bfr[NW];
#pragma unroll
    for (int m = 0; m < 4; ++m)
      af[m] = *reinterpret_cast<const s16x8*>(&As[cur][wRow + m * 16 + lr][lg * 8]);
#pragma unroll
    for (int n = 0; n < NW; ++n)
      bfr[n] = *reinterpret_cast<const s16x8*>(&Bs[cur][wCol + n * 16 + lr][lg * 8]);
#pragma unroll
    for (int m = 0; m < 4; ++m)
#pragma unroll
      for (int n = 0; n < NW; ++n)
        acc[m][n] = __builtin_amdgcn_mfma_f32_16x16x32_bf16(af[m], bfr[n], acc[m][n], 0, 0, 0);

    asm volatile("s_waitcnt lgkmcnt(0)" ::: "memory");
    __builtin_amdgcn_s_barrier();
    __builtin_amdgcn_sched_barrier(0);
  }

  // ---- epilogue ----
  ushort* CbOut = Cb;
  int colBase = bCol, Ncols = nbx * BN, third = 0;
  if (QKV) {
    third = bCol >> 10;
    CbOut = Cb + (size_t)third * ROWS * DM;
    colBase = bCol & 1023;
    Ncols = DM;
  }
#pragma unroll
  for (int m = 0; m < 4; ++m) {
    int gr = bRow + wRow + m * 16 + lg * 4;
#pragma unroll
    for (int n = 0; n < NW; ++n) {
      int gc = colBase + wCol + n * 16 + lr;
      if (QKV && third == 2) {
        // V-third: fused transpose to vT[bh][d][n], 8-chunk swizzled
        int h = gc >> 6, d = gc & 63;
        int b = gr >> 11, ntok = gr & (NN - 1);
        size_t basev = ((size_t)(b * HH + h) * DK + d) * NN;
        int nb = ntok & ~63, c = (ntok >> 3) & 7, j0 = ntok & 7;
        ushort4 ov;
        ov.x = f2bf(acc[m][n][0]);
        ov.y = f2bf(acc[m][n][1]);
        ov.z = f2bf(acc[m][n][2]);
        ov.w = f2bf(acc[m][n][3]);
        ushort* VT = Cb + (size_t)3 * ROWS * DM;   // vtb region
        *reinterpret_cast<ushort4*>(VT + basev + nb + ((c ^ (d & 7)) << 3) + j0) = ov;
        continue;
      }
      float bv = (EPI == 1 || EPI == 2) ? bias[gc] : 0.0f;
#pragma unroll
      for (int r = 0; r < 4; ++r) {
        int nr = gr + r;
        float v = acc[m][n][r] + bv;
        if (EPI == 3) {
          Cb[((size_t)kc * ROWS + nr) * Ncols + gc] = f2bf(v);   // bf16 partial
        } else if (EPI == 2) {
          size_t idx = (size_t)nr * Ncols + gc;
          Cf[idx] = v + bf2f(resid[idx]);
        } else if (EPI == 1) {
          size_t idx = (size_t)nr * Ncols + gc;
          float u = v + 0.044715f * v * v * v;
          float g = v / (1.0f + __expf(-1.5957691216057308f * u));
          CbOut[idx] = f2bf(g);
        } else {
          int gcs = gc;
          if (QKV && third == 1)   // pre-swizzle K rows for attn's linear gload_lds
            gcs = (gc & ~63) | ((gc ^ ((nr & 7) << 3)) & 63);
          CbOut[(size_t)nr * Ncols + gcs] = f2bf(v);
        }
      }
    }
  }
}

// ---------------- LayerNorm over D=1024 rows ----------------
// MODE 0: in f32 -> outb bf16 only (LN1).
// MODE 1: in bf16 + p0 + p1 (bf16 split-K partials) + pb reduce -> outf f32 (LN2).
template <int MODE>
__global__ __launch_bounds__(256) void k_ln(const void* __restrict__ inp,
                                            const ushort* __restrict__ p0,
                                            const ushort* __restrict__ p1,
                                            const float* __restrict__ pb,
                                            const float* __restrict__ g,
                                            const float* __restrict__ bta,
                                            float* __restrict__ outf,
                                            ushort* __restrict__ outb) {
  const int row = blockIdx.x;
  const int t = threadIdx.x;
  float4 v;
  if (MODE == 0) {
    v = reinterpret_cast<const float4*>((const float*)inp + (size_t)row * DM)[t];
  } else {
    ushort4 xv = reinterpret_cast<const ushort4*>((const ushort*)inp + (size_t)row * DM)[t];
    ushort4 a = reinterpret_cast<const ushort4*>(p0 + (size_t)row * DM)[t];
    ushort4 b = reinterpret_cast<const ushort4*>(p1 + (size_t)row * DM)[t];
    float4 c = reinterpret_cast<const float4*>(pb)[t];
    v.x = bf2f(xv.x) + bf2f(a.x) + bf2f(b.x) + c.x;
    v.y = bf2f(xv.y) + bf2f(a.y) + bf2f(b.y) + c.y;
    v.z = bf2f(xv.z) + bf2f(a.z) + bf2f(b.z) + c.z;
    v.w = bf2f(xv.w) + bf2f(a.w) + bf2f(b.w) + c.w;
  }
  float s1 = v.x + v.y + v.z + v.w;
  float s2 = v.x * v.x + v.y * v.y + v.z * v.z + v.w * v.w;
#pragma unroll
  for (int m = 32; m; m >>= 1) {
    s1 += __shfl_xor(s1, m, 64);
    s2 += __shfl_xor(s2, m, 64);
  }
  __shared__ float red[2][4];
  if ((t & 63) == 0) { red[0][t >> 6] = s1; red[1][t >> 6] = s2; }
  __syncthreads();
  s1 = red[0][0] + red[0][1] + red[0][2] + red[0][3];
  s2 = red[1][0] + red[1][1] + red[1][2] + red[1][3];
  const float mu = s1 * (1.0f / DM);
  const float var = s2 * (1.0f / DM) - mu * mu;
  const float rstd = rsqrtf(var + 1e-5f);
  float4 gv = reinterpret_cast<const float4*>(g)[t];
  float4 bv = reinterpret_cast<const float4*>(bta)[t];
  float4 o;
  o.x = (v.x - mu) * rstd * gv.x + bv.x;
  o.y = (v.y - mu) * rstd * gv.y + bv.y;
  o.z = (v.z - mu) * rstd * gv.z + bv.z;
  o.w = (v.w - mu) * rstd * gv.w + bv.w;
  if (MODE == 1) {
    reinterpret_cast<float4*>(outf + (size_t)row * DM)[t] = o;
  } else {
    ushort4 ob;
    ob.x = f2bf(o.x); ob.y = f2bf(o.y); ob.z = f2bf(o.z); ob.w = f2bf(o.w);
    reinterpret_cast<ushort4*>(outb + (size_t)row * DM)[t] = ob;
  }
}

// ---------------- causal flash attention: XCD-pinned, <=8-tile segments ----
static __device__ const unsigned char SCHED40[40][2] = {
  {15,0},{15,1},{15,2},{15,3}, {14,0},{14,1},{14,2},{14,3},
  {13,0},{13,1},{13,2},{13,3}, {12,0},{12,1},{12,2},{12,3},
  {11,0},{11,1},{11,2}, {10,0},{10,1},{10,2},
  {9,0},{9,1},{9,2}, {8,0},{8,1},{8,2},
  {7,0},{7,1}, {6,0},{6,1}, {5,0},{5,1}, {4,0},{4,1},
  {3,0},{2,0},{1,0},{0,0}};

__global__ __launch_bounds__(256) void k_attn(const ushort* __restrict__ Q,
                                              const ushort* __restrict__ Kb,
                                              const ushort* __restrict__ vT,
                                              ushort* __restrict__ O,
                                              float* __restrict__ Op,
                                              float* __restrict__ ml) {
  __shared__ ushort Ks[2][64 * 64];
  __shared__ ushort Vs[2][64 * 64];

  const int t = threadIdx.x;
  const int bid = blockIdx.x;
  const int xcd = bid & 7, j = bid >> 3;    // j in [0,160)
  const int head = j & 3, e = j >> 2;       // e in [0,40)
  const int qi = SCHED40[e][0], seg = SCHED40[e][1];
  const int bh = xcd * 4 + head;
  const int ntiles = 2 * qi + 2;
  const int nseg = (2 * qi + 9) >> 3;       // 1,2,3,4
  const int tb = ntiles / nseg, rem = ntiles % nseg;
  const int kt0 = seg * tb + (seg < rem ? seg : rem);
  const int kt1 = kt0 + tb + (seg < rem ? 1 : 0);

  const int lane = t & 63, wid = t >> 6;
  const int l31 = lane & 31, hi = lane >> 5;
  const int q0w = qi * 128 + wid * 32;
  const size_t qbase = ((size_t)(bh >> 4) * NN) * DM + (bh & 15) * DK;
  const size_t vbase = (size_t)bh * DK * NN;

  const float C = 0.18033688011112043f;   // 0.125 * log2(e)
  const float THR = 44.3614195558365f;    // 8 / C: defer-rescale threshold (T13)

  s16x8 qf[4];
#pragma unroll
  for (int c = 0; c < 4; ++c)
    qf[c] = *reinterpret_cast<const s16x8*>(Q + qbase + (size_t)(q0w + l31) * DM + c * 16 + hi * 8);

  float mrun = -1e30f, negcm = 1e30f;
  float lsum[16];                 // deferred per-lane partial sums
#pragma unroll
  for (int i = 0; i < 16; ++i) lsum[i] = 0.f;
  f32x16 accO[2];
#pragma unroll
  for (int dt = 0; dt < 2; ++dt)
#pragma unroll
    for (int r = 0; r < 16; ++r) accO[dt][r] = 0.f;

  auto stage = [&](int buf, int kt) {
    const int kk = kt * 64;
#pragma unroll
    for (int i = 0; i < 2; ++i) {
      int row0 = wid * 16 + i * 8;
      __builtin_amdgcn_global_load_lds(
          AS1(Kb + qbase + (size_t)(kk + row0 + (lane >> 3)) * DM + (lane & 7) * 8),
          AS3(&Ks[buf][row0 * 64]), 16, 0, 0);
      __builtin_amdgcn_global_load_lds(
          AS1(vT + vbase + (size_t)(row0 + (lane >> 3)) * NN + kk + (lane & 7) * 8),
          AS3(&Vs[buf][row0 * 64]), 16, 0, 0);
    }
  };

  stage(0, kt0);
  for (int kt = kt0, li = 0; kt < kt1; ++kt, ++li) {
    const int cur = li & 1;
    const int kk = kt * 64;
    __syncthreads();
    if (kt + 1 < kt1) stage(cur ^ 1, kt + 1);

    if (kk <= q0w + 31) {
      const char* KsB = (const char*)Ks[cur];
      const char* VsB = (const char*)Vs[cur];
      const bool diag = (kk + 64 > q0w);
      const int nsub = (kk + 32 <= q0w + 31) ? 2 : 1;   // wave-uniform

      f32x16 st[2];
      __builtin_amdgcn_s_setprio(1);
#pragma unroll
      for (int sub = 0; sub < 2; ++sub) {
        if (sub >= nsub) break;
#pragma unroll
        for (int r = 0; r < 16; ++r) st[sub][r] = 0.f;
        const int row = sub * 32 + l31;
        const int swz = (row & 7) << 4;
#pragma unroll
        for (int c = 0; c < 4; ++c) {
          s16x8 kf = *reinterpret_cast<const s16x8*>(KsB + row * 128 + ((c * 32 + hi * 16) ^ swz));
          st[sub] = __builtin_amdgcn_mfma_f32_32x32x16_bf16(kf, qf[c], st[sub], 0, 0, 0);
        }
      }
      __builtin_amdgcn_s_setprio(0);

      const int q = q0w + l31;
      float p[32];
#pragma unroll
      for (int sub = 0; sub < 2; ++sub) {
        if (sub >= nsub) break;
#pragma unroll
        for (int r = 0; r < 16; ++r) {
          float v = st[sub][r];
          if (diag) {
            int kl = sub * 32 + (r & 3) + 8 * (r >> 2) + 4 * hi;
            if (kk + kl > q) v = -1e30f;
          }
          p[sub * 16 + r] = v;
        }
      }
      float m8[8];
#pragma unroll
      for (int i = 0; i < 8; ++i) {
        float x = fmaxf(p[i], p[i + 8]);
        if (nsub == 2) x = fmaxf(fmaxf(p[i + 16], p[i + 24]), x);
        m8[i] = x;
      }
      float rm = fmaxf(fmaxf(fmaxf(m8[0], m8[1]), fmaxf(m8[2], m8[3])),
                       fmaxf(fmaxf(m8[4], m8[5]), fmaxf(m8[6], m8[7])));
      rm = fmaxf(rm, __shfl_xor(rm, 32, 64));

      // T13 defer-rescale: only rescale when the max grows past THR (P <= 2^8)
      if (__any(rm > mrun + THR)) {
        const float mn = fmaxf(mrun, rm);
        const float alpha = fexp2(C * (mrun - mn));
        mrun = mn;
        negcm = -C * mn;
#pragma unroll
        for (int i = 0; i < 16; ++i) lsum[i] *= alpha;
#pragma unroll
        for (int dt = 0; dt < 2; ++dt) accO[dt] *= alpha;
      }

#pragma unroll
      for (int sub = 0; sub < 2; ++sub) {
        if (sub >= nsub) break;
#pragma unroll
        for (int i = 0; i < 16; ++i)
          p[sub * 16 + i] = fexp2(fmaf(p[sub * 16 + i], C, negcm));
      }
      // deferred sum: accumulate per-lane partials only (tree once at end)
#pragma unroll
      for (int i = 0; i < 16; ++i)
        lsum[i] += (nsub == 2) ? (p[i] + p[i + 16]) : p[i];

      s16x8 pf[4];
#pragma unroll
      for (int sub = 0; sub < 2; ++sub) {
        if (sub >= nsub) break;
#pragma unroll
        for (int hf = 0; hf < 2; ++hf) {
          const float* pp = &p[sub * 16 + hf * 8];
          unsigned X0 = cvtpk(pp[0], pp[1]);
          unsigned X1 = cvtpk(pp[2], pp[3]);
          unsigned Y0 = cvtpk(pp[4], pp[5]);
          unsigned Y1 = cvtpk(pp[6], pp[7]);
          asm volatile("v_permlane32_swap_b32 %0, %1" : "+v"(X0), "+v"(Y0));
          asm volatile("v_permlane32_swap_b32 %0, %1" : "+v"(X1), "+v"(Y1));
          union { unsigned u[4]; s16x8 v; } uu;
          uu.u[0] = X0; uu.u[1] = X1; uu.u[2] = Y0; uu.u[3] = Y1;
          pf[sub * 2 + hf] = uu.v;
        }
      }

      __builtin_amdgcn_s_setprio(1);
#pragma unroll
      for (int dt = 0; dt < 2; ++dt) {
        const int d = dt * 32 + l31;
        const int vswz = (d & 7) << 4;
#pragma unroll
        for (int kc = 0; kc < 4; ++kc) {
          if (kc >= nsub * 2) break;
          s16x8 vf = *reinterpret_cast<const s16x8*>(VsB + d * 128 + ((kc * 32 + hi * 16) ^ vswz));
          accO[dt] = __builtin_amdgcn_mfma_f32_32x32x16_bf16(vf, pf[kc], accO[dt], 0, 0, 0);
        }
      }
      __builtin_amdgcn_s_setprio(0);
    }
  }

  // ---- final lrun reduction (deferred) ----
#pragma unroll
  for (int s = 8; s; s >>= 1)
#pragma unroll
    for (int i = 0; i < 8; ++i) if (i < s) lsum[i] += lsum[i + s];
  float lrun = lsum[0] + __shfl_xor(lsum[0], 32, 64);

  // ---- epilogue ----
  if (nseg == 1) {
    const int q = q0w + l31;
    const float inv = 1.0f / lrun;
#pragma unroll
    for (int dt = 0; dt < 2; ++dt)
#pragma unroll
      for (int rg = 0; rg < 4; ++rg) {
        int d0 = 8 * rg + 4 * hi + 32 * dt;
        ushort4 ov;
        ov.x = f2bf(accO[dt][rg * 4 + 0] * inv);
        ov.y = f2bf(accO[dt][rg * 4 + 1] * inv);
        ov.z = f2bf(accO[dt][rg * 4 + 2] * inv);
        ov.w = f2bf(accO[dt][rg * 4 + 3] * inv);
        *reinterpret_cast<ushort4*>(O + qbase + (size_t)q * DM + d0) = ov;
      }
  } else {
    const int pidx = (bh * 12 + (qi - 4)) * 4 + seg;
    float* op = Op + (size_t)pidx * (128 * 64);
    const int row = wid * 32 + l31;
#pragma unroll
    for (int dt = 0; dt < 2; ++dt)
#pragma unroll
      for (int rg = 0; rg < 4; ++rg) {
        int d0 = 8 * rg + 4 * hi + 32 * dt;
        f32x4 v4 = { accO[dt][rg * 4 + 0], accO[dt][rg * 4 + 1],
                     accO[dt][rg * 4 + 2], accO[dt][rg * 4 + 3] };
        *reinterpret_cast<f32x4*>(op + (size_t)row * 64 + d0) = v4;
      }
    if (hi == 0) {
      ml[(size_t)pidx * 256 + row * 2 + 0] = mrun;
      ml[(size_t)pidx * 256 + row * 2 + 1] = lrun;
    }
  }
}

// ---------------- merge split-KV partials (up to 4-way) ----------------
__global__ __launch_bounds__(256) void k_amerge(const float* __restrict__ Op,
                                                const float* __restrict__ ml,
                                                ushort* __restrict__ O) {
  const int bid = blockIdx.x;
  const int bh = bid / 12, qq = bid % 12;
  const int qi = qq + 4;
  const int nseg = (2 * qi + 9) >> 3;       // 2,3,4
  const int t = threadIdx.x;
  const int row = t >> 1, dh = (t & 1) * 32;
  const float C = 0.18033688011112043f;
  const int pbase = (bh * 12 + qq) * 4;

  float M = -1e30f;
  for (int s = 0; s < nseg; ++s)
    M = fmaxf(M, ml[(size_t)(pbase + s) * 256 + row * 2 + 0]);
  float wsum = 0.f;
  for (int s = 0; s < nseg; ++s) {
    float ms = ml[(size_t)(pbase + s) * 256 + row * 2 + 0];
    float ls = ml[(size_t)(pbase + s) * 256 + row * 2 + 1];
    wsum += ls * fexp2(C * (ms - M));
  }
  const float inv = 1.0f / wsum;

  f32x4 acc[8];
#pragma unroll
  for (int i = 0; i < 8; ++i) acc[i] = (f32x4){0.f, 0.f, 0.f, 0.f};
  for (int s = 0; s < nseg; ++s) {
    float wsc = fexp2(C * (ml[(size_t)(pbase + s) * 256 + row * 2 + 0] - M));
    const float* os = Op + (size_t)(pbase + s) * (128 * 64) + (size_t)row * 64 + dh;
#pragma unroll
    for (int i = 0; i < 8; ++i) {
      f32x4 v = reinterpret_cast<const f32x4*>(os)[i];
      acc[i] += v * wsc;
    }
  }

  const int b = bh >> 4, h = bh & 15;
  const int n = qi * 128 + row;
  ushort* dst = O + ((size_t)(b * NN + n)) * DM + h * DK + dh;
#pragma unroll
  for (int i = 0; i < 8; ++i) {
    ushort4 ov;
    ov.x = f2bf(acc[i][0] * inv);
    ov.y = f2bf(acc[i][1] * inv);
    ov.z = f2bf(acc[i][2] * inv);
    ov.w = f2bf(acc[i][3] * inv);
    reinterpret_cast<ushort4*>(dst)[i] = ov;
  }
}

// ---------------- launch ----------------
extern "C" void kernel_launch(void* const* d_in, const int* in_sizes, int n_in,
                              void* d_out, int out_size, void* d_ws, size_t ws_size,
                              hipStream_t stream) {
  const float* tgt = (const float*)d_in[0];
  const float* Wq  = (const float*)d_in[3];
  const float* Wk  = (const float*)d_in[4];
  const float* Wv  = (const float*)d_in[5];
  const float* Wo  = (const float*)d_in[6];
  const float* bo  = (const float*)d_in[7];
  const float* W1  = (const float*)d_in[8];
  const float* b1  = (const float*)d_in[9];
  const float* W2  = (const float*)d_in[10];
  const float* b2  = (const float*)d_in[11];
  const float* g1  = (const float*)d_in[12];
  const float* be1 = (const float*)d_in[13];
  const float* g2  = (const float*)d_in[14];
  const float* be2 = (const float*)d_in[15];

  char* ws = (char*)d_ws;
  size_t off = 0;
  auto alloc = [&](size_t bytes) {
    void* p = ws + off;
    off += (bytes + 255) & ~(size_t)255;
    return p;
  };
  ushort* xb   = (ushort*)alloc((size_t)ROWS * DM * 2);
  ushort* wqb  = (ushort*)alloc((size_t)DM * DM * 2);   // wq|wk|wv contiguous
  ushort* wkb  = (ushort*)alloc((size_t)DM * DM * 2);
  ushort* wvb  = (ushort*)alloc((size_t)DM * DM * 2);
  ushort* wob  = (ushort*)alloc((size_t)DM * DM * 2);
  ushort* w1b  = (ushort*)alloc((size_t)FF * DM * 2);
  ushort* w2b  = (ushort*)alloc((size_t)DM * FF * 2);
  ushort* qbuf = (ushort*)alloc((size_t)ROWS * DM * 2); // q|k|v|vT contiguous
  ushort* kbuf = (ushort*)alloc((size_t)ROWS * DM * 2);
  ushort* vbuf = (ushort*)alloc((size_t)ROWS * DM * 2); // unused (V fused to vT)
  ushort* vtb  = (ushort*)alloc((size_t)ROWS * DM * 2);
  ushort* atnb = (ushort*)alloc((size_t)ROWS * DM * 2);
  float*  h1   = (float*)alloc((size_t)ROWS * DM * 4);
  float*  x1f  = (float*)alloc((size_t)ROWS * DM * 4);  // kept for layout (unused)
  ushort* x1b  = (ushort*)alloc((size_t)ROWS * DM * 2);
  ushort* t1b  = (ushort*)alloc((size_t)ROWS * FF * 2);
  float*  mlb  = (float*)alloc((size_t)1536 * 256 * 4);      // m,l partials
  float*  Opb  = h1;             // attn O-partials overlay dead h1/x1f region
  ushort* ppb  = (ushort*)qbuf;  // FFN2 bf16 split-K partials overlay dead q/k
  (void)ws_size; (void)in_sizes; (void)n_in; (void)out_size;
  (void)wkb; (void)wvb; (void)kbuf; (void)vbuf; (void)vtb; (void)x1f;

  dim3 blk(256);
  k_cast7<<<dim3(16384), blk, 0, stream>>>(tgt, Wq, Wk, Wv, Wo, W1, W2,
                                           xb, wqb, w1b, w2b);

  // fused QKV (K-third pre-swizzled; V-third fused transpose -> vtb)
  k_gemm<0, 128, true, 1><<<dim3(24 * 32), blk, 0, stream>>>(
      xb, wqb, nullptr, nullptr, qbuf, nullptr, DM, 24);

  k_attn<<<dim3(1280), blk, 0, stream>>>(qbuf, kbuf, vtb, atnb, Opb, mlb);
  k_amerge<<<dim3(384), blk, 0, stream>>>(Opb, mlb, atnb);

  // O-projection + bo + residual(xb, bf16) -> f32 h1 (overwrites dead partials)
  k_gemm<2, 64, false, 1><<<dim3(16 * 32), blk, 0, stream>>>(
      atnb, wob, bo, xb, nullptr, h1, DM, 16);
  // LN1: h1 -> x1b (bf16 only)
  k_ln<0><<<dim3(ROWS), blk, 0, stream>>>(h1, nullptr, nullptr, nullptr,
                                          g1, be1, nullptr, x1b);

  // FFN1
  k_gemm<1, 128, false, 1><<<dim3(32 * 32), blk, 0, stream>>>(
      x1b, w1b, b1, nullptr, t1b, nullptr, DM, 32);
  // FFN2: split-K=2, bf16 partials into ppb (q/k region, now dead)
  k_gemm<3, 64, false, 2><<<dim3(2 * 16 * 32), blk, 0, stream>>>(
      t1b, w2b, nullptr, nullptr, ppb, nullptr, FF, 16);
  // LN2: x1b(bf16) + bf16 split-K reduce + b2 -> d_out (f32)
  k_ln<1><<<dim3(ROWS), blk, 0, stream>>>(x1b, ppb, ppb + (size_t)ROWS * DM, b2,
                                          g2, be2, (float*)d_out, nullptr);
}